// Round 7
// baseline (2860.456 us; speedup 1.0000x reference)
//
#include <hip/hip_runtime.h>
#include <hip/hip_cooperative_groups.h>

namespace cg = cooperative_groups;

#define T_STEPS 8192
#define SIT     64
#define SS      256
#define S2      512
#define NPL     32000
#define NEV     (2*T_STEPS)
#define MAXLEV  255
#define RELAX   48
#define NKB     (S2/4)    // 128 k-blocks for U part
#define WKB     (SIT/4)   // 16 k-blocks for W part
#define BQMAX   16

__device__ __forceinline__ float sigmoidf_(float x) {
    return 1.0f / (1.0f + expf(-x));
}
__device__ __forceinline__ float dot4_(float4 a, float4 b) {
    return a.x*b.x + a.y*b.y + a.z*b.z + a.w*b.w;
}

// ---------------- preprocessing kernels ----------------

__global__ void k_zero(int* cnt) {
    int i = blockIdx.x * blockDim.x + threadIdx.x;
    if (i < NPL) cnt[i] = 0;
}

__global__ void k_count(const int* __restrict__ b, const int* __restrict__ p, int* cnt) {
    int e = blockIdx.x * blockDim.x + threadIdx.x;
    if (e < NEV) {
        int v = (e & 1) ? p[e >> 1] : b[e >> 1];
        atomicAdd(&cnt[v], 1);
    }
}

__global__ __launch_bounds__(1024) void k_scan(const int* __restrict__ cnt, int* bas, int* cur) {
    __shared__ int partial[1024];
    int tid = threadIdx.x;
    int start = tid * 32;
    int end = start + 32; if (end > NPL) end = NPL;
    int s = 0;
    for (int i = start; i < end; ++i) s += cnt[i];
    partial[tid] = s;
    __syncthreads();
    for (int off = 1; off < 1024; off <<= 1) {
        int v = partial[tid];
        int add = (tid >= off) ? partial[tid - off] : 0;
        __syncthreads();
        partial[tid] = v + add;
        __syncthreads();
    }
    int acc = (tid == 0) ? 0 : partial[tid - 1];
    for (int i = start; i < end; ++i) {
        bas[i] = acc; cur[i] = acc; acc += cnt[i];
    }
}

__global__ void k_place(const int* __restrict__ b, const int* __restrict__ p, int* cur, int* list) {
    int e = blockIdx.x * blockDim.x + threadIdx.x;
    if (e < NEV) {
        int v = (e & 1) ? p[e >> 1] : b[e >> 1];
        int pos = atomicAdd(&cur[v], 1);
        list[pos] = e;
    }
}

__global__ void k_pred(const int* __restrict__ bas, const int* __restrict__ cnt, int* list, int* pred) {
    int v = blockIdx.x * blockDim.x + threadIdx.x;
    if (v >= NPL) return;
    int s0 = bas[v], c = cnt[v];
    for (int i2 = 1; i2 < c; ++i2) {
        int key = list[s0 + i2];
        int j = i2 - 1;
        while (j >= 0 && list[s0 + j] > key) { list[s0 + j + 1] = list[s0 + j]; --j; }
        list[s0 + j + 1] = key;
    }
    int prevS = -1, curS = -1;
    for (int i2 = 0; i2 < c; ++i2) {
        int e = list[s0 + i2];
        int s = e >> 1;
        if (s != curS) { prevS = curS; curS = s; }
        pred[e] = prevS;
    }
}

__global__ __launch_bounds__(1024) void k_levels(const int* __restrict__ pred,
                                                 int* order, int* levelStart, int* numLevels) {
    __shared__ short p0[T_STEPS], p1[T_STEPS];
    __shared__ unsigned char lev[T_STEPS];
    __shared__ int cnts[MAXLEV + 2];
    __shared__ int maxLev;
    int tid = threadIdx.x;
    for (int t = tid; t < T_STEPS; t += 1024) {
        p0[t] = (short)pred[2 * t];
        p1[t] = (short)pred[2 * t + 1];
        lev[t] = 1;
    }
    for (int l = tid; l < MAXLEV + 2; l += 1024) cnts[l] = 0;
    if (tid == 0) maxLev = 0;
    __syncthreads();
    for (int r = 0; r < RELAX; ++r) {
        for (int t = tid; t < T_STEPS; t += 1024) {
            int a = p0[t], b2 = p1[t];
            int la = (a >= 0) ? (int)lev[a] : 0;
            int lb = (b2 >= 0) ? (int)lev[b2] : 0;
            int nl = 1 + (la > lb ? la : lb);
            if (nl > MAXLEV) nl = MAXLEV;
            if (nl > (int)lev[t]) lev[t] = (unsigned char)nl;
        }
        __syncthreads();
    }
    for (int t = tid; t < T_STEPS; t += 1024) {
        atomicAdd(&cnts[lev[t]], 1);
        atomicMax(&maxLev, (int)lev[t]);
    }
    __syncthreads();
    if (tid == 0) {
        int acc = 0;
        levelStart[0] = 0;
        for (int l = 1; l <= maxLev; ++l) {
            int c = cnts[l];
            cnts[l] = acc;
            acc += c;
            levelStart[l] = acc;
        }
        *numLevels = maxLev;
    }
    __syncthreads();
    for (int t = tid; t < T_STEPS; t += 1024) {
        int pos = atomicAdd(&cnts[lev[t]], 1);
        order[pos] = t;
    }
}

// fused transpose of all 6 matrices into [k/4][512][4] layout
__global__ void k_trans(const float* __restrict__ Uz, const float* __restrict__ Ur,
                        const float* __restrict__ Uh, const float* __restrict__ Wz,
                        const float* __restrict__ Wr, const float* __restrict__ Wh,
                        float* UzT, float* UrT, float* UhT,
                        float* WzT, float* WrT, float* WhT) {
    int y = blockIdx.y;
    int idx = blockIdx.x * blockDim.x + threadIdx.x;
    if (y < 3) {
        const float* S = (y == 0) ? Uz : (y == 1) ? Ur : Uh;
        float*       D = (y == 0) ? UzT : (y == 1) ? UrT : UhT;
        if (idx < S2 * S2) {
            int i2 = idx / S2, k = idx % S2;
            D[((k >> 2) * S2 + i2) * 4 + (k & 3)] = S[idx];
        }
    } else {
        const float* S = (y == 3) ? Wz : (y == 4) ? Wr : Wh;
        float*       D = (y == 3) ? WzT : (y == 4) ? WrT : WhT;
        if (idx < S2 * SIT) {
            int i2 = idx / SIT, k = idx % SIT;
            D[((k >> 2) * S2 + i2) * 4 + (k & 3)] = S[idx];
        }
    }
}

__global__ void k_copy(const float4* __restrict__ src, float4* dst, int n4) {
    int i = blockIdx.x * blockDim.x + threadIdx.x;
    if (i < n4) dst[i] = src[i];
}

// XP = W@x + bias for all steps (non-cooperative; one 16-step tile per block)
__global__ __launch_bounds__(512) void k_xp(
    const float* __restrict__ x,
    const float* __restrict__ WzT, const float* __restrict__ WrT, const float* __restrict__ WhT,
    const float* __restrict__ bz, const float* __restrict__ br, const float* __restrict__ bh,
    float* __restrict__ XPz, float* __restrict__ XPr, float* __restrict__ XPh)
{
    __shared__ float xs[16][SIT];
    const int i = threadIdx.x;
    const int tile = blockIdx.x;              // 0 .. T_STEPS/16-1
    const float4* Wz4 = (const float4*)WzT;
    const float4* Wr4 = (const float4*)WrT;
    const float4* Wh4 = (const float4*)WhT;
    const float bzi = bz[i], bri = br[i], bhi = bh[i];

    for (int idx = i; idx < 16 * SIT; idx += 512) {
        int j = idx >> 6, k = idx & (SIT - 1);
        xs[j][k] = x[(tile * 16 + j) * SIT + k];
    }
    __syncthreads();
    float za[16], ra[16], ha[16];
#pragma unroll
    for (int j = 0; j < 16; ++j) { za[j] = 0.f; ra[j] = 0.f; ha[j] = 0.f; }
    for (int kb = 0; kb < WKB; ++kb) {
        float4 wz = Wz4[kb * S2 + i];
        float4 wr = Wr4[kb * S2 + i];
        float4 wh = Wh4[kb * S2 + i];
#pragma unroll
        for (int j = 0; j < 16; ++j) {
            float4 x4 = *(const float4*)(&xs[j][kb * 4]);
            za[j] += dot4_(wz, x4);
            ra[j] += dot4_(wr, x4);
            ha[j] += dot4_(wh, x4);
        }
    }
#pragma unroll
    for (int j = 0; j < 16; ++j) {
        int t = tile * 16 + j;
        XPz[t * S2 + i] = za[j] + bzi;
        XPr[t * S2 + i] = ra[j] - bri;
        XPh[t * S2 + i] = ha[j] + bhi;
    }
}

// ---------------- main cooperative kernel ----------------

template<int BQ>
__device__ __forceinline__ void process_level(
    int s0, int s1, int i, int useXP,
    const float* __restrict__ x,
    const int* __restrict__ bArr, const int* __restrict__ pArr,
    const float4* __restrict__ Wz4, const float4* __restrict__ Wr4, const float4* __restrict__ Wh4,
    const float4* __restrict__ Uz4, const float4* __restrict__ Ur4, const float4* __restrict__ Uh4,
    const float* __restrict__ XPz, const float* __restrict__ XPr, const float* __restrict__ XPh,
    float bzi, float bri, float bhi,
    float* __restrict__ out, const int* __restrict__ order,
    float (*Hs)[S2], float (*RHs)[S2], float (*xs)[SIT],
    int* tj, int* rbs, int* rps)
{
    const int nT = (s1 - s0 + BQ - 1) / BQ;
    for (int tile = blockIdx.x; tile < nT; tile += gridDim.x) {
        const int sbase = s0 + tile * BQ;
        const int B = (sbase + BQ <= s1) ? BQ : (s1 - sbase);
        __syncthreads();                       // guard LDS reuse from previous tile
        if (i < BQ) {
            int t = (i < B) ? order[sbase + i] : -1;
            tj[i] = t;
            rbs[i] = (t >= 0) ? bArr[t] : 0;
            rps[i] = (t >= 0) ? pArr[t] : 0;
        }
        __syncthreads();

        // gather h = concat(table[b], table[p]) per step
        for (int idx = i; idx < BQ * S2; idx += 512) {
            int j = idx >> 9, k = idx & (S2 - 1);
            float v = 0.0f;
            if (tj[j] >= 0) {
                int row = (k < SS) ? rbs[j] : rps[j];
                v = out[row * SS + (k & (SS - 1))];
            }
            Hs[j][k] = v;
        }
        if (!useXP) {
            for (int idx = i; idx < BQ * SIT; idx += 512) {
                int j = idx >> 6, k = idx & (SIT - 1);
                int t = tj[j];
                xs[j][k] = (t >= 0) ? x[t * SIT + k] : 0.0f;
            }
        }
        // init accumulators (XP holds W@x with biases folded)
        float zacc[BQ], racc[BQ];
        if (useXP) {
#pragma unroll
            for (int j = 0; j < BQ; ++j) {
                int t = tj[j];
                zacc[j] = (t >= 0) ? XPz[t * S2 + i] : 0.0f;
                racc[j] = (t >= 0) ? XPr[t * S2 + i] : 0.0f;
            }
        } else {
#pragma unroll
            for (int j = 0; j < BQ; ++j) { zacc[j] = 0.0f; racc[j] = 0.0f; }
        }
        __syncthreads();                       // Hs (and xs) ready

        if (!useXP) {
            for (int kb = 0; kb < WKB; ++kb) {
                float4 a4 = Wz4[kb * S2 + i];
                float4 b4 = Wr4[kb * S2 + i];
#pragma unroll
                for (int j = 0; j < BQ; ++j) {
                    float4 x4 = *(const float4*)(&xs[j][kb * 4]);
                    zacc[j] += dot4_(a4, x4);
                    racc[j] += dot4_(b4, x4);
                }
            }
        }
        // U z/r loop: groups of 4 kb-steps, 8 loads issued up front (ILP
        // covers L2 latency; compute per group 512-1024cy >> ~300cy).
        {
#pragma unroll 1
            for (int kb = 0; kb < NKB; kb += 4) {
                float4 uz[4], ur[4];
#pragma unroll
                for (int q = 0; q < 4; ++q) {
                    uz[q] = Uz4[(kb + q) * S2 + i];
                    ur[q] = Ur4[(kb + q) * S2 + i];
                }
#pragma unroll
                for (int q = 0; q < 4; ++q) {
#pragma unroll
                    for (int j = 0; j < BQ; ++j) {
                        float4 h4 = *(const float4*)(&Hs[j][(kb + q) * 4]);
                        zacc[j] += dot4_(uz[q], h4);
                        racc[j] += dot4_(ur[q], h4);
                    }
                }
            }
        }
        float zv[BQ];
#pragma unroll
        for (int j = 0; j < BQ; ++j) {
            zv[j] = sigmoidf_(useXP ? zacc[j] : (zacc[j] + bzi));
            float rv = sigmoidf_(useXP ? racc[j] : (racc[j] - bri));
            RHs[j][i] = rv * Hs[j][i];
        }
        __syncthreads();                       // RHs ready

        // phase B: m
        float macc[BQ];
        if (useXP) {
#pragma unroll
            for (int j = 0; j < BQ; ++j) {
                int t = tj[j];
                macc[j] = (t >= 0) ? XPh[t * S2 + i] : 0.0f;
            }
        } else {
#pragma unroll
            for (int j = 0; j < BQ; ++j) macc[j] = 0.0f;
            for (int kb = 0; kb < WKB; ++kb) {
                float4 a4 = Wh4[kb * S2 + i];
#pragma unroll
                for (int j = 0; j < BQ; ++j) {
                    float4 x4 = *(const float4*)(&xs[j][kb * 4]);
                    macc[j] += dot4_(a4, x4);
                }
            }
        }
        {
#pragma unroll 1
            for (int kb = 0; kb < NKB; kb += 4) {
                float4 uh[4];
#pragma unroll
                for (int q = 0; q < 4; ++q) {
                    uh[q] = Uh4[(kb + q) * S2 + i];
                }
#pragma unroll
                for (int q = 0; q < 4; ++q) {
#pragma unroll
                    for (int j = 0; j < BQ; ++j) {
                        float4 h4 = *(const float4*)(&RHs[j][(kb + q) * 4]);
                        macc[j] += dot4_(uh[q], h4);
                    }
                }
            }
        }
        // scatter
        for (int j = 0; j < B; ++j) {
            float mm = tanhf(useXP ? macc[j] : (macc[j] + bhi));
            float h = Hs[j][i];
            float hn = zv[j] * h + (1.0f - zv[j]) * mm;
            int rb = rbs[j], rp = rps[j];
            int row = (i < SS) ? rb : rp;
            float* addr = out + row * SS + (i & (SS - 1));
            if (rb == rp) atomicAdd(addr, hn - h);
            else *addr = hn;
        }
    }
}

__global__ __launch_bounds__(512, 4) void k_main(
    const float* __restrict__ x, const int* __restrict__ bArr, const int* __restrict__ pArr,
    const float* __restrict__ WzT, const float* __restrict__ WrT, const float* __restrict__ WhT,
    const float* __restrict__ UzT, const float* __restrict__ UrT, const float* __restrict__ UhT,
    const float* __restrict__ bz, const float* __restrict__ br, const float* __restrict__ bh,
    float* __restrict__ out,
    const int* __restrict__ order, const int* __restrict__ levelStart,
    const int* __restrict__ numLevels,
    const float* __restrict__ XPz, const float* __restrict__ XPr, const float* __restrict__ XPh,
    int useXP)
{
    cg::grid_group grid = cg::this_grid();
    __shared__ float Hs[BQMAX][S2];
    __shared__ float RHs[BQMAX][S2];
    __shared__ float xs[BQMAX][SIT];
    __shared__ int tj[BQMAX], rbs[BQMAX], rps[BQMAX];

    const int i = threadIdx.x;
    const float bzi = bz[i], bri = br[i], bhi = bh[i];
    const float4* Uz4 = (const float4*)UzT;
    const float4* Ur4 = (const float4*)UrT;
    const float4* Uh4 = (const float4*)UhT;
    const float4* Wz4 = (const float4*)WzT;
    const float4* Wr4 = (const float4*)WrT;
    const float4* Wh4 = (const float4*)WhT;

    const int nLev = *numLevels;
    for (int lvl = 1; lvl <= nLev; ++lvl) {
        const int s0 = levelStart[lvl - 1], s1 = levelStart[lvl];
        const int n = s1 - s0;
        // BQ tier: big levels amortize the 3MB U-stream; small levels
        // minimize per-round VALU (round-quantized wall model).
        if (n > 3000)
            process_level<16>(s0, s1, i, useXP, x, bArr, pArr, Wz4, Wr4, Wh4,
                              Uz4, Ur4, Uh4, XPz, XPr, XPh, bzi, bri, bhi,
                              out, order, Hs, RHs, xs, tj, rbs, rps);
        else if (n > 1000)
            process_level<8>(s0, s1, i, useXP, x, bArr, pArr, Wz4, Wr4, Wh4,
                             Uz4, Ur4, Uh4, XPz, XPr, XPh, bzi, bri, bhi,
                             out, order, Hs, RHs, xs, tj, rbs, rps);
        else if (n > 400)
            process_level<4>(s0, s1, i, useXP, x, bArr, pArr, Wz4, Wr4, Wh4,
                             Uz4, Ur4, Uh4, XPz, XPr, XPh, bzi, bri, bhi,
                             out, order, Hs, RHs, xs, tj, rbs, rps);
        else if (n > 120)
            process_level<2>(s0, s1, i, useXP, x, bArr, pArr, Wz4, Wr4, Wh4,
                             Uz4, Ur4, Uh4, XPz, XPr, XPh, bzi, bri, bhi,
                             out, order, Hs, RHs, xs, tj, rbs, rps);
        else
            process_level<1>(s0, s1, i, useXP, x, bArr, pArr, Wz4, Wr4, Wh4,
                             Uz4, Ur4, Uh4, XPz, XPr, XPh, bzi, bri, bhi,
                             out, order, Hs, RHs, xs, tj, rbs, rps);
        grid.sync();
    }
}

// ---------------- host launcher ----------------

extern "C" void kernel_launch(void* const* d_in, const int* in_sizes, int n_in,
                              void* d_out, int out_size, void* d_ws, size_t ws_size,
                              hipStream_t stream) {
    const float* x  = (const float*)d_in[0];
    const int*   b  = (const int*)d_in[1];
    const int*   p  = (const int*)d_in[2];
    const float* Wz = (const float*)d_in[3];
    const float* Wr = (const float*)d_in[4];
    const float* Wh = (const float*)d_in[5];
    const float* Uz = (const float*)d_in[6];
    const float* Ur = (const float*)d_in[7];
    const float* Uh = (const float*)d_in[8];
    const float* bz = (const float*)d_in[9];
    const float* br = (const float*)d_in[10];
    const float* bh = (const float*)d_in[11];
    const float* table0 = (const float*)d_in[12];
    float* out = (float*)d_out;

    float* UzT = (float*)d_ws;
    float* UrT = UzT + S2 * S2;
    float* UhT = UrT + S2 * S2;
    float* WzT = UhT + S2 * S2;
    float* WrT = WzT + S2 * SIT;
    float* WhT = WrT + S2 * SIT;
    int* cnt = (int*)(WhT + S2 * SIT);
    int* cur = cnt + NPL;
    int* bas = cur + NPL;
    int* list = bas + NPL;
    int* pred = list + NEV;
    int* order = pred + NEV;
    int* levelStart = order + T_STEPS;
    int* numLevels = levelStart + 260;

    size_t baseFloats = (size_t)(3 * S2 * S2 + 3 * S2 * SIT) + 3 * NPL + 2 * NEV + T_STEPS + 261;
    baseFloats = (baseFloats + 255) & ~(size_t)255;
    float* XPz = (float*)d_ws + baseFloats;
    float* XPr = XPz + (size_t)T_STEPS * S2;
    float* XPh = XPr + (size_t)T_STEPS * S2;
    size_t needBytes = (baseFloats + 3ull * T_STEPS * S2) * 4ull;
    int useXP = (ws_size >= needBytes) ? 1 : 0;

    hipLaunchKernelGGL(k_trans, dim3(1024, 6), dim3(256), 0, stream,
                       Uz, Ur, Uh, Wz, Wr, Wh, UzT, UrT, UhT, WzT, WrT, WhT);
    hipLaunchKernelGGL(k_zero, dim3((NPL + 255) / 256), dim3(256), 0, stream, cnt);
    hipLaunchKernelGGL(k_count, dim3((NEV + 255) / 256), dim3(256), 0, stream, b, p, cnt);
    hipLaunchKernelGGL(k_scan, dim3(1), dim3(1024), 0, stream, cnt, bas, cur);
    hipLaunchKernelGGL(k_place, dim3((NEV + 255) / 256), dim3(256), 0, stream, b, p, cur, list);
    hipLaunchKernelGGL(k_pred, dim3((NPL + 255) / 256), dim3(256), 0, stream, bas, cnt, list, pred);
    hipLaunchKernelGGL(k_levels, dim3(1), dim3(1024), 0, stream, pred, order, levelStart, numLevels);

    int n4 = NPL * SS / 4;
    hipLaunchKernelGGL(k_copy, dim3((n4 + 255) / 256), dim3(256), 0, stream,
                       (const float4*)table0, (float4*)out, n4);
    if (useXP) {
        hipLaunchKernelGGL(k_xp, dim3(T_STEPS / 16), dim3(512), 0, stream,
                           x, WzT, WrT, WhT, bz, br, bh, XPz, XPr, XPh);
    }

    // grid sizing: query capacity, clamp DOWN only (never exceed what fits)
    int occ = 0;
    if (hipOccupancyMaxActiveBlocksPerMultiprocessor(&occ, k_main, 512, 0) != hipSuccess)
        occ = 1;
    if (occ < 1) occ = 1;
    if (occ > 2) occ = 2;
    int gridSz = occ * 256;

    void* args[] = {
        (void*)&x, (void*)&b, (void*)&p,
        (void*)&WzT, (void*)&WrT, (void*)&WhT,
        (void*)&UzT, (void*)&UrT, (void*)&UhT,
        (void*)&bz, (void*)&br, (void*)&bh,
        (void*)&out,
        (void*)&order, (void*)&levelStart, (void*)&numLevels,
        (void*)&XPz, (void*)&XPr, (void*)&XPh, (void*)&useXP
    };
    hipError_t e = hipLaunchCooperativeKernel((void*)k_main, dim3(gridSz), dim3(512), args, 0, stream);
    if (e != hipSuccess && gridSz != 256) {
        hipLaunchCooperativeKernel((void*)k_main, dim3(256), dim3(512), args, 0, stream);
    }
}

// Round 8
// 1244.281 us; speedup vs baseline: 2.2989x; 2.2989x over previous
//
#include <hip/hip_runtime.h>
#include <hip/hip_cooperative_groups.h>

namespace cg = cooperative_groups;

#define T_STEPS 8192
#define SIT     64
#define SS      256
#define S2      512
#define NPL     32000
#define NEV     (2*T_STEPS)
#define MAXLEV  255
#define RELAX   48
#define NKB     (S2/4)    // 128 k-blocks for U part
#define WKB     (SIT/4)   // 16 k-blocks for W part
#define BQMAX   16
#define CUTN    300       // levels larger than this run in phase A (tile mode)

__device__ __forceinline__ float sigmoidf_(float x) {
    return 1.0f / (1.0f + expf(-x));
}
__device__ __forceinline__ float dot4_(float4 a, float4 b) {
    return a.x*b.x + a.y*b.y + a.z*b.z + a.w*b.w;
}
__device__ __forceinline__ float loadLLC_(float* p) {
    return __hip_atomic_load(p, __ATOMIC_RELAXED, __HIP_MEMORY_SCOPE_AGENT);
}
__device__ __forceinline__ void storeLLC_(float* p, float v) {
    __hip_atomic_store(p, v, __ATOMIC_RELAXED, __HIP_MEMORY_SCOPE_AGENT);
}

// ---------------- preprocessing kernels ----------------

__global__ void k_zero(int* cnt) {
    int i = blockIdx.x * blockDim.x + threadIdx.x;
    if (i < NPL) cnt[i] = 0;
}

__global__ void k_count(const int* __restrict__ b, const int* __restrict__ p, int* cnt) {
    int e = blockIdx.x * blockDim.x + threadIdx.x;
    if (e < NEV) {
        int v = (e & 1) ? p[e >> 1] : b[e >> 1];
        atomicAdd(&cnt[v], 1);
    }
}

__global__ __launch_bounds__(1024) void k_scan(const int* __restrict__ cnt, int* bas, int* cur) {
    __shared__ int partial[1024];
    int tid = threadIdx.x;
    int start = tid * 32;
    int end = start + 32; if (end > NPL) end = NPL;
    int s = 0;
    for (int i = start; i < end; ++i) s += cnt[i];
    partial[tid] = s;
    __syncthreads();
    for (int off = 1; off < 1024; off <<= 1) {
        int v = partial[tid];
        int add = (tid >= off) ? partial[tid - off] : 0;
        __syncthreads();
        partial[tid] = v + add;
        __syncthreads();
    }
    int acc = (tid == 0) ? 0 : partial[tid - 1];
    for (int i = start; i < end; ++i) {
        bas[i] = acc; cur[i] = acc; acc += cnt[i];
    }
}

__global__ void k_place(const int* __restrict__ b, const int* __restrict__ p, int* cur, int* list) {
    int e = blockIdx.x * blockDim.x + threadIdx.x;
    if (e < NEV) {
        int v = (e & 1) ? p[e >> 1] : b[e >> 1];
        int pos = atomicAdd(&cur[v], 1);
        list[pos] = e;
    }
}

__global__ void k_pred(const int* __restrict__ bas, const int* __restrict__ cnt, int* list, int* pred) {
    int v = blockIdx.x * blockDim.x + threadIdx.x;
    if (v >= NPL) return;
    int s0 = bas[v], c = cnt[v];
    for (int i2 = 1; i2 < c; ++i2) {
        int key = list[s0 + i2];
        int j = i2 - 1;
        while (j >= 0 && list[s0 + j] > key) { list[s0 + j + 1] = list[s0 + j]; --j; }
        list[s0 + j + 1] = key;
    }
    int prevS = -1, curS = -1;
    for (int i2 = 0; i2 < c; ++i2) {
        int e = list[s0 + i2];
        int s = e >> 1;
        if (s != curS) { prevS = curS; curS = s; }
        pred[e] = prevS;
    }
}

__global__ __launch_bounds__(1024) void k_levels(const int* __restrict__ pred,
                                                 int* order, int* levelStart, int* numLevels,
                                                 int* levArr) {
    __shared__ short p0[T_STEPS], p1[T_STEPS];
    __shared__ unsigned char lev[T_STEPS];
    __shared__ int cnts[MAXLEV + 2];
    __shared__ int maxLev;
    int tid = threadIdx.x;
    for (int t = tid; t < T_STEPS; t += 1024) {
        p0[t] = (short)pred[2 * t];
        p1[t] = (short)pred[2 * t + 1];
        lev[t] = 1;
    }
    for (int l = tid; l < MAXLEV + 2; l += 1024) cnts[l] = 0;
    if (tid == 0) maxLev = 0;
    __syncthreads();
    for (int r = 0; r < RELAX; ++r) {
        for (int t = tid; t < T_STEPS; t += 1024) {
            int a = p0[t], b2 = p1[t];
            int la = (a >= 0) ? (int)lev[a] : 0;
            int lb = (b2 >= 0) ? (int)lev[b2] : 0;
            int nl = 1 + (la > lb ? la : lb);
            if (nl > MAXLEV) nl = MAXLEV;
            if (nl > (int)lev[t]) lev[t] = (unsigned char)nl;
        }
        __syncthreads();
    }
    for (int t = tid; t < T_STEPS; t += 1024) {
        atomicAdd(&cnts[lev[t]], 1);
        atomicMax(&maxLev, (int)lev[t]);
    }
    __syncthreads();
    if (tid == 0) {
        int acc = 0;
        levelStart[0] = 0;
        int cut = 0, stopped = 0;
        for (int l = 1; l <= maxLev; ++l) {
            int c = cnts[l];
            if (!stopped) { if (c > CUTN) cut = l; else stopped = 1; }
            cnts[l] = acc;
            acc += c;
            levelStart[l] = acc;
        }
        numLevels[0] = maxLev;
        numLevels[1] = cut;
    }
    __syncthreads();
    for (int t = tid; t < T_STEPS; t += 1024) {
        int pos = atomicAdd(&cnts[lev[t]], 1);
        order[pos] = t;
        levArr[t] = (int)lev[t];
    }
}

// fused transpose of all 6 matrices into [k/4][512][4] layout
__global__ void k_trans(const float* __restrict__ Uz, const float* __restrict__ Ur,
                        const float* __restrict__ Uh, const float* __restrict__ Wz,
                        const float* __restrict__ Wr, const float* __restrict__ Wh,
                        float* UzT, float* UrT, float* UhT,
                        float* WzT, float* WrT, float* WhT) {
    int y = blockIdx.y;
    int idx = blockIdx.x * blockDim.x + threadIdx.x;
    if (y < 3) {
        const float* S = (y == 0) ? Uz : (y == 1) ? Ur : Uh;
        float*       D = (y == 0) ? UzT : (y == 1) ? UrT : UhT;
        if (idx < S2 * S2) {
            int i2 = idx / S2, k = idx % S2;
            D[((k >> 2) * S2 + i2) * 4 + (k & 3)] = S[idx];
        }
    } else {
        const float* S = (y == 3) ? Wz : (y == 4) ? Wr : Wh;
        float*       D = (y == 3) ? WzT : (y == 4) ? WrT : WhT;
        if (idx < S2 * SIT) {
            int i2 = idx / SIT, k = idx % SIT;
            D[((k >> 2) * S2 + i2) * 4 + (k & 3)] = S[idx];
        }
    }
}

__global__ void k_copy(const float4* __restrict__ src, float4* dst, int n4) {
    int i = blockIdx.x * blockDim.x + threadIdx.x;
    if (i < n4) dst[i] = src[i];
}

// XP = W@x + bias for all steps (non-cooperative; one 16-step tile per block)
__global__ __launch_bounds__(512) void k_xp(
    const float* __restrict__ x,
    const float* __restrict__ WzT, const float* __restrict__ WrT, const float* __restrict__ WhT,
    const float* __restrict__ bz, const float* __restrict__ br, const float* __restrict__ bh,
    float* __restrict__ XPz, float* __restrict__ XPr, float* __restrict__ XPh)
{
    __shared__ float xs[16][SIT];
    const int i = threadIdx.x;
    const int tile = blockIdx.x;
    const float4* Wz4 = (const float4*)WzT;
    const float4* Wr4 = (const float4*)WrT;
    const float4* Wh4 = (const float4*)WhT;
    const float bzi = bz[i], bri = br[i], bhi = bh[i];

    for (int idx = i; idx < 16 * SIT; idx += 512) {
        int j = idx >> 6, k = idx & (SIT - 1);
        xs[j][k] = x[(tile * 16 + j) * SIT + k];
    }
    __syncthreads();
    float za[16], ra[16], ha[16];
#pragma unroll
    for (int j = 0; j < 16; ++j) { za[j] = 0.f; ra[j] = 0.f; ha[j] = 0.f; }
    for (int kb = 0; kb < WKB; ++kb) {
        float4 wz = Wz4[kb * S2 + i];
        float4 wr = Wr4[kb * S2 + i];
        float4 wh = Wh4[kb * S2 + i];
#pragma unroll
        for (int j = 0; j < 16; ++j) {
            float4 x4 = *(const float4*)(&xs[j][kb * 4]);
            za[j] += dot4_(wz, x4);
            ra[j] += dot4_(wr, x4);
            ha[j] += dot4_(wh, x4);
        }
    }
#pragma unroll
    for (int j = 0; j < 16; ++j) {
        int t = tile * 16 + j;
        XPz[t * S2 + i] = za[j] + bzi;
        XPr[t * S2 + i] = ra[j] - bri;
        XPh[t * S2 + i] = ha[j] + bhi;
    }
}

// ---------------- main cooperative kernel ----------------

// Phase A: R4-proven tile body; out[] via LLC-coherent (sc1) accesses.
template<int BQ>
__device__ __forceinline__ void process_level(
    int s0, int s1, int i, int useXP,
    const float* __restrict__ x,
    const int* __restrict__ bArr, const int* __restrict__ pArr,
    const float4* __restrict__ Wz4, const float4* __restrict__ Wr4, const float4* __restrict__ Wh4,
    const float4* __restrict__ Uz4, const float4* __restrict__ Ur4, const float4* __restrict__ Uh4,
    const float* __restrict__ XPz, const float* __restrict__ XPr, const float* __restrict__ XPh,
    float bzi, float bri, float bhi,
    float* __restrict__ out, const int* __restrict__ order,
    float (*Hs)[S2], float (*RHs)[S2], float (*xs)[SIT],
    int* tj, int* rbs, int* rps)
{
    const int nT = (s1 - s0 + BQ - 1) / BQ;
    for (int tile = blockIdx.x; tile < nT; tile += gridDim.x) {
        const int sbase = s0 + tile * BQ;
        const int B = (sbase + BQ <= s1) ? BQ : (s1 - sbase);
        __syncthreads();
        if (i < BQ) {
            int t = (i < B) ? order[sbase + i] : -1;
            tj[i] = t;
            rbs[i] = (t >= 0) ? bArr[t] : 0;
            rps[i] = (t >= 0) ? pArr[t] : 0;
        }
        __syncthreads();

        for (int idx = i; idx < BQ * S2; idx += 512) {
            int j = idx >> 9, k = idx & (S2 - 1);
            float v = 0.0f;
            if (tj[j] >= 0) {
                int row = (k < SS) ? rbs[j] : rps[j];
                v = loadLLC_(out + row * SS + (k & (SS - 1)));
            }
            Hs[j][k] = v;
        }
        if (!useXP) {
            for (int idx = i; idx < BQ * SIT; idx += 512) {
                int j = idx >> 6, k = idx & (SIT - 1);
                int t = tj[j];
                xs[j][k] = (t >= 0) ? x[t * SIT + k] : 0.0f;
            }
        }
        float zacc[BQ], racc[BQ];
        if (useXP) {
#pragma unroll
            for (int j = 0; j < BQ; ++j) {
                int t = tj[j];
                zacc[j] = (t >= 0) ? XPz[t * S2 + i] : 0.0f;
                racc[j] = (t >= 0) ? XPr[t * S2 + i] : 0.0f;
            }
        } else {
#pragma unroll
            for (int j = 0; j < BQ; ++j) { zacc[j] = 0.0f; racc[j] = 0.0f; }
        }
        __syncthreads();

        if (!useXP) {
            for (int kb = 0; kb < WKB; ++kb) {
                float4 a4 = Wz4[kb * S2 + i];
                float4 b4 = Wr4[kb * S2 + i];
#pragma unroll
                for (int j = 0; j < BQ; ++j) {
                    float4 x4 = *(const float4*)(&xs[j][kb * 4]);
                    zacc[j] += dot4_(a4, x4);
                    racc[j] += dot4_(b4, x4);
                }
            }
        }
        for (int kb = 0; kb < NKB; ++kb) {
            float4 a4 = Uz4[kb * S2 + i];
            float4 b4 = Ur4[kb * S2 + i];
#pragma unroll
            for (int j = 0; j < BQ; ++j) {
                float4 h4 = *(const float4*)(&Hs[j][kb * 4]);
                zacc[j] += dot4_(a4, h4);
                racc[j] += dot4_(b4, h4);
            }
        }
        float zv[BQ];
#pragma unroll
        for (int j = 0; j < BQ; ++j) {
            zv[j] = sigmoidf_(useXP ? zacc[j] : (zacc[j] + bzi));
            float rv = sigmoidf_(useXP ? racc[j] : (racc[j] - bri));
            RHs[j][i] = rv * Hs[j][i];
        }
        __syncthreads();

        float macc[BQ];
        if (useXP) {
#pragma unroll
            for (int j = 0; j < BQ; ++j) {
                int t = tj[j];
                macc[j] = (t >= 0) ? XPh[t * S2 + i] : 0.0f;
            }
        } else {
#pragma unroll
            for (int j = 0; j < BQ; ++j) macc[j] = 0.0f;
            for (int kb = 0; kb < WKB; ++kb) {
                float4 a4 = Wh4[kb * S2 + i];
#pragma unroll
                for (int j = 0; j < BQ; ++j) {
                    float4 x4 = *(const float4*)(&xs[j][kb * 4]);
                    macc[j] += dot4_(a4, x4);
                }
            }
        }
        for (int kb = 0; kb < NKB; ++kb) {
            float4 a4 = Uh4[kb * S2 + i];
#pragma unroll
            for (int j = 0; j < BQ; ++j) {
                float4 h4 = *(const float4*)(&RHs[j][kb * 4]);
                macc[j] += dot4_(a4, h4);
            }
        }
        for (int j = 0; j < B; ++j) {
            float mm = tanhf(useXP ? macc[j] : (macc[j] + bhi));
            float h = Hs[j][i];
            float hn = zv[j] * h + (1.0f - zv[j]) * mm;
            int rb = rbs[j], rp = rps[j];
            int row = (i < SS) ? rb : rp;
            float* addr = out + row * SS + (i & (SS - 1));
            if (rb == rp) atomicAdd(addr, hn - h);
            else storeLLC_(addr, hn);
        }
    }
}

__global__ __launch_bounds__(512, 4) void k_main(
    const float* __restrict__ x, const int* __restrict__ bArr, const int* __restrict__ pArr,
    const float* __restrict__ WzT, const float* __restrict__ WrT, const float* __restrict__ WhT,
    const float* __restrict__ UzT, const float* __restrict__ UrT, const float* __restrict__ UhT,
    const float* __restrict__ bz, const float* __restrict__ br, const float* __restrict__ bh,
    float* __restrict__ out,
    const int* __restrict__ order, const int* __restrict__ levelStart,
    const int* __restrict__ numLevels,
    const float* __restrict__ XPz, const float* __restrict__ XPr, const float* __restrict__ XPh,
    const int* __restrict__ pred, const int* __restrict__ levArr, int* __restrict__ flagArr,
    int useXP)
{
    cg::grid_group grid = cg::this_grid();
    __shared__ float Hs[BQMAX][S2];
    __shared__ float RHs[BQMAX][S2];
    __shared__ float xs[BQMAX][SIT];
    __shared__ int tj[BQMAX], rbs[BQMAX], rps[BQMAX];

    const int i = threadIdx.x;
    const float bzi = bz[i], bri = br[i], bhi = bh[i];
    const float4* Uz4 = (const float4*)UzT;
    const float4* Ur4 = (const float4*)UrT;
    const float4* Uh4 = (const float4*)UhT;
    const float4* Wz4 = (const float4*)WzT;
    const float4* Wr4 = (const float4*)WrT;
    const float4* Wh4 = (const float4*)WhT;

    const int cutoff = numLevels[1];

    // ---- phase A: big levels, tile mode ----
    for (int lvl = 1; lvl <= cutoff; ++lvl) {
        const int s0 = levelStart[lvl - 1], s1 = levelStart[lvl];
        const int n = s1 - s0;
        if (n > 3000)
            process_level<16>(s0, s1, i, useXP, x, bArr, pArr, Wz4, Wr4, Wh4,
                              Uz4, Ur4, Uh4, XPz, XPr, XPh, bzi, bri, bhi,
                              out, order, Hs, RHs, xs, tj, rbs, rps);
        else if (n > 1000)
            process_level<8>(s0, s1, i, useXP, x, bArr, pArr, Wz4, Wr4, Wh4,
                             Uz4, Ur4, Uh4, XPz, XPr, XPh, bzi, bri, bhi,
                             out, order, Hs, RHs, xs, tj, rbs, rps);
        else
            process_level<4>(s0, s1, i, useXP, x, bArr, pArr, Wz4, Wr4, Wh4,
                             Uz4, Ur4, Uh4, XPz, XPr, XPh, bzi, bri, bhi,
                             out, order, Hs, RHs, xs, tj, rbs, rps);
        grid.sync();
    }

    // ---- init flags: phase-A steps done, phase-B steps pending ----
    for (int t = blockIdx.x * 512 + i; t < T_STEPS; t += gridDim.x * 512)
        flagArr[t] = (levArr[t] <= cutoff) ? 1 : 0;
    grid.sync();

    // ---- phase B: dataflow chain mode (no grid.sync, U stays L2-hot) ----
    float* Hs0 = &Hs[0][0];
    float* RHs0 = &RHs[0][0];
    float* xs0 = &xs[0][0];
    for (int t = blockIdx.x; t < T_STEPS; t += gridDim.x) {
        if (levArr[t] <= cutoff) continue;
        // wait for predecessors (thread 0 spins, LLC-coherent flag reads)
        if (i == 0) {
            int p0 = pred[2 * t], p1 = pred[2 * t + 1];
            while (p0 >= 0 && __hip_atomic_load(&flagArr[p0], __ATOMIC_RELAXED,
                                                __HIP_MEMORY_SCOPE_AGENT) == 0)
                __builtin_amdgcn_s_sleep(2);
            while (p1 >= 0 && __hip_atomic_load(&flagArr[p1], __ATOMIC_RELAXED,
                                                __HIP_MEMORY_SCOPE_AGENT) == 0)
                __builtin_amdgcn_s_sleep(2);
        }
        __syncthreads();

        const int rb = bArr[t], rp = pArr[t];
        const int row = (i < SS) ? rb : rp;
        float* addr = out + row * SS + (i & (SS - 1));
        const float h = loadLLC_(addr);
        Hs0[i] = h;
        float zacc, racc;
        if (useXP) {
            zacc = XPz[t * S2 + i];
            racc = XPr[t * S2 + i];
        } else {
            zacc = 0.0f; racc = 0.0f;
            if (i < SIT) xs0[i] = x[t * SIT + i];
        }
        __syncthreads();

        if (!useXP) {
            for (int kb = 0; kb < WKB; ++kb) {
                float4 a4 = Wz4[kb * S2 + i];
                float4 b4 = Wr4[kb * S2 + i];
                float4 x4 = *(const float4*)(&xs0[kb * 4]);
                zacc += dot4_(a4, x4);
                racc += dot4_(b4, x4);
            }
        }
        for (int kb = 0; kb < NKB; ++kb) {
            float4 a4 = Uz4[kb * S2 + i];
            float4 b4 = Ur4[kb * S2 + i];
            float4 h4 = *(const float4*)(&Hs0[kb * 4]);
            zacc += dot4_(a4, h4);
            racc += dot4_(b4, h4);
        }
        const float zv = sigmoidf_(useXP ? zacc : (zacc + bzi));
        const float rv = sigmoidf_(useXP ? racc : (racc - bri));
        RHs0[i] = rv * h;
        __syncthreads();

        float macc;
        if (useXP) {
            macc = XPh[t * S2 + i];
        } else {
            macc = 0.0f;
            for (int kb = 0; kb < WKB; ++kb) {
                float4 a4 = Wh4[kb * S2 + i];
                float4 x4 = *(const float4*)(&xs0[kb * 4]);
                macc += dot4_(a4, x4);
            }
        }
        for (int kb = 0; kb < NKB; ++kb) {
            float4 a4 = Uh4[kb * S2 + i];
            float4 h4 = *(const float4*)(&RHs0[kb * 4]);
            macc += dot4_(a4, h4);
        }
        const float mm = tanhf(useXP ? macc : (macc + bhi));
        const float hn = zv * h + (1.0f - zv) * mm;
        if (rb == rp) atomicAdd(addr, hn - h);
        else storeLLC_(addr, hn);
        __syncthreads();   // all lanes' stores complete (waitcnt before barrier)
        if (i == 0)
            __hip_atomic_store(&flagArr[t], 1, __ATOMIC_RELEASE, __HIP_MEMORY_SCOPE_AGENT);
    }
}

// ---------------- host launcher ----------------

extern "C" void kernel_launch(void* const* d_in, const int* in_sizes, int n_in,
                              void* d_out, int out_size, void* d_ws, size_t ws_size,
                              hipStream_t stream) {
    const float* x  = (const float*)d_in[0];
    const int*   b  = (const int*)d_in[1];
    const int*   p  = (const int*)d_in[2];
    const float* Wz = (const float*)d_in[3];
    const float* Wr = (const float*)d_in[4];
    const float* Wh = (const float*)d_in[5];
    const float* Uz = (const float*)d_in[6];
    const float* Ur = (const float*)d_in[7];
    const float* Uh = (const float*)d_in[8];
    const float* bz = (const float*)d_in[9];
    const float* br = (const float*)d_in[10];
    const float* bh = (const float*)d_in[11];
    const float* table0 = (const float*)d_in[12];
    float* out = (float*)d_out;

    float* UzT = (float*)d_ws;
    float* UrT = UzT + S2 * S2;
    float* UhT = UrT + S2 * S2;
    float* WzT = UhT + S2 * S2;
    float* WrT = WzT + S2 * SIT;
    float* WhT = WrT + S2 * SIT;
    int* cnt = (int*)(WhT + S2 * SIT);
    int* cur = cnt + NPL;
    int* bas = cur + NPL;
    int* list = bas + NPL;
    int* pred = list + NEV;
    int* order = pred + NEV;
    int* levelStart = order + T_STEPS;
    int* numLevels = levelStart + 260;   // [0]=maxLev, [1]=cutoff (+2 pad)
    int* levArr = numLevels + 4;
    int* flagArr = levArr + T_STEPS;

    size_t baseFloats = (size_t)(3 * S2 * S2 + 3 * S2 * SIT)
                      + 3 * NPL + 2 * NEV + 3 * T_STEPS + 264;
    baseFloats = (baseFloats + 255) & ~(size_t)255;
    float* XPz = (float*)d_ws + baseFloats;
    float* XPr = XPz + (size_t)T_STEPS * S2;
    float* XPh = XPr + (size_t)T_STEPS * S2;
    size_t needBytes = (baseFloats + 3ull * T_STEPS * S2) * 4ull;
    int useXP = (ws_size >= needBytes) ? 1 : 0;

    hipLaunchKernelGGL(k_trans, dim3(1024, 6), dim3(256), 0, stream,
                       Uz, Ur, Uh, Wz, Wr, Wh, UzT, UrT, UhT, WzT, WrT, WhT);
    hipLaunchKernelGGL(k_zero, dim3((NPL + 255) / 256), dim3(256), 0, stream, cnt);
    hipLaunchKernelGGL(k_count, dim3((NEV + 255) / 256), dim3(256), 0, stream, b, p, cnt);
    hipLaunchKernelGGL(k_scan, dim3(1), dim3(1024), 0, stream, cnt, bas, cur);
    hipLaunchKernelGGL(k_place, dim3((NEV + 255) / 256), dim3(256), 0, stream, b, p, cur, list);
    hipLaunchKernelGGL(k_pred, dim3((NPL + 255) / 256), dim3(256), 0, stream, bas, cnt, list, pred);
    hipLaunchKernelGGL(k_levels, dim3(1), dim3(1024), 0, stream,
                       pred, order, levelStart, numLevels, levArr);

    int n4 = NPL * SS / 4;
    hipLaunchKernelGGL(k_copy, dim3((n4 + 255) / 256), dim3(256), 0, stream,
                       (const float4*)table0, (float4*)out, n4);
    if (useXP) {
        hipLaunchKernelGGL(k_xp, dim3(T_STEPS / 16), dim3(512), 0, stream,
                           x, WzT, WrT, WhT, bz, br, bh, XPz, XPr, XPh);
    }

    // grid sizing: query capacity, clamp DOWN only (never exceed what fits)
    int occ = 0;
    if (hipOccupancyMaxActiveBlocksPerMultiprocessor(&occ, k_main, 512, 0) != hipSuccess)
        occ = 1;
    if (occ < 1) occ = 1;
    if (occ > 2) occ = 2;
    int gridSz = occ * 256;

    void* args[] = {
        (void*)&x, (void*)&b, (void*)&p,
        (void*)&WzT, (void*)&WrT, (void*)&WhT,
        (void*)&UzT, (void*)&UrT, (void*)&UhT,
        (void*)&bz, (void*)&br, (void*)&bh,
        (void*)&out,
        (void*)&order, (void*)&levelStart, (void*)&numLevels,
        (void*)&XPz, (void*)&XPr, (void*)&XPh,
        (void*)&pred, (void*)&levArr, (void*)&flagArr, (void*)&useXP
    };
    hipError_t e = hipLaunchCooperativeKernel((void*)k_main, dim3(gridSz), dim3(512), args, 0, stream);
    if (e != hipSuccess && gridSz != 256) {
        hipLaunchCooperativeKernel((void*)k_main, dim3(256), dim3(512), args, 0, stream);
    }
}

// Round 9
// 1132.140 us; speedup vs baseline: 2.5266x; 1.0991x over previous
//
#include <hip/hip_runtime.h>
#include <hip/hip_cooperative_groups.h>

namespace cg = cooperative_groups;

#define T_STEPS 8192
#define SIT     64
#define SS      256
#define S2      512
#define NPL     32000
#define NEV     (2*T_STEPS)
#define MAXLEV  255
#define RELAX   48
#define NKB     (S2/4)    // 128 k-blocks for U part
#define WKB     (SIT/4)   // 16 k-blocks for W part
#define BQMAX   16
#define CUTN    300       // levels larger than this run in phase A (tile mode)

__device__ __forceinline__ float sigmoidf_(float x) {
    return 1.0f / (1.0f + expf(-x));
}
__device__ __forceinline__ float dot4_(float4 a, float4 b) {
    return a.x*b.x + a.y*b.y + a.z*b.z + a.w*b.w;
}
__device__ __forceinline__ float loadLLC_(float* p) {
    return __hip_atomic_load(p, __ATOMIC_RELAXED, __HIP_MEMORY_SCOPE_AGENT);
}
__device__ __forceinline__ void storeLLC_(float* p, float v) {
    __hip_atomic_store(p, v, __ATOMIC_RELAXED, __HIP_MEMORY_SCOPE_AGENT);
}

// ---------------- preprocessing kernels ----------------

__global__ void k_zero(int* cnt) {
    int i = blockIdx.x * blockDim.x + threadIdx.x;
    if (i < NPL) cnt[i] = 0;
}

__global__ void k_count(const int* __restrict__ b, const int* __restrict__ p, int* cnt) {
    int e = blockIdx.x * blockDim.x + threadIdx.x;
    if (e < NEV) {
        int v = (e & 1) ? p[e >> 1] : b[e >> 1];
        atomicAdd(&cnt[v], 1);
    }
}

__global__ __launch_bounds__(1024) void k_scan(const int* __restrict__ cnt, int* bas, int* cur) {
    __shared__ int partial[1024];
    int tid = threadIdx.x;
    int start = tid * 32;
    int end = start + 32; if (end > NPL) end = NPL;
    int s = 0;
    for (int i = start; i < end; ++i) s += cnt[i];
    partial[tid] = s;
    __syncthreads();
    for (int off = 1; off < 1024; off <<= 1) {
        int v = partial[tid];
        int add = (tid >= off) ? partial[tid - off] : 0;
        __syncthreads();
        partial[tid] = v + add;
        __syncthreads();
    }
    int acc = (tid == 0) ? 0 : partial[tid - 1];
    for (int i = start; i < end; ++i) {
        bas[i] = acc; cur[i] = acc; acc += cnt[i];
    }
}

__global__ void k_place(const int* __restrict__ b, const int* __restrict__ p, int* cur, int* list) {
    int e = blockIdx.x * blockDim.x + threadIdx.x;
    if (e < NEV) {
        int v = (e & 1) ? p[e >> 1] : b[e >> 1];
        int pos = atomicAdd(&cur[v], 1);
        list[pos] = e;
    }
}

__global__ void k_pred(const int* __restrict__ bas, const int* __restrict__ cnt, int* list, int* pred) {
    int v = blockIdx.x * blockDim.x + threadIdx.x;
    if (v >= NPL) return;
    int s0 = bas[v], c = cnt[v];
    for (int i2 = 1; i2 < c; ++i2) {
        int key = list[s0 + i2];
        int j = i2 - 1;
        while (j >= 0 && list[s0 + j] > key) { list[s0 + j + 1] = list[s0 + j]; --j; }
        list[s0 + j + 1] = key;
    }
    int prevS = -1, curS = -1;
    for (int i2 = 0; i2 < c; ++i2) {
        int e = list[s0 + i2];
        int s = e >> 1;
        if (s != curS) { prevS = curS; curS = s; }
        pred[e] = prevS;
    }
}

__global__ __launch_bounds__(1024) void k_levels(const int* __restrict__ pred,
                                                 int* order, int* levelStart, int* numLevels,
                                                 int* levArr) {
    __shared__ short p0[T_STEPS], p1[T_STEPS];
    __shared__ unsigned char lev[T_STEPS];
    __shared__ int cnts[MAXLEV + 2];
    __shared__ int maxLev;
    __shared__ int changed;
    int tid = threadIdx.x;
    for (int t = tid; t < T_STEPS; t += 1024) {
        p0[t] = (short)pred[2 * t];
        p1[t] = (short)pred[2 * t + 1];
        lev[t] = 1;
    }
    for (int l = tid; l < MAXLEV + 2; l += 1024) cnts[l] = 0;
    if (tid == 0) maxLev = 0;
    __syncthreads();
    for (int r = 0; r < RELAX; ++r) {
        if (tid == 0) changed = 0;
        __syncthreads();                      // reset visible before updates
        for (int t = tid; t < T_STEPS; t += 1024) {
            int a = p0[t], b2 = p1[t];
            int la = (a >= 0) ? (int)lev[a] : 0;
            int lb = (b2 >= 0) ? (int)lev[b2] : 0;
            int nl = 1 + (la > lb ? la : lb);
            if (nl > MAXLEV) nl = MAXLEV;
            if (nl > (int)lev[t]) { lev[t] = (unsigned char)nl; changed = 1; }
        }
        __syncthreads();                      // updates done
        int ch = changed;
        __syncthreads();                      // all read before next reset
        if (!ch) break;                       // uniform exit (fixpoint)
    }
    for (int t = tid; t < T_STEPS; t += 1024) {
        atomicAdd(&cnts[lev[t]], 1);
        atomicMax(&maxLev, (int)lev[t]);
    }
    __syncthreads();
    if (tid == 0) {
        int acc = 0;
        levelStart[0] = 0;
        int cut = 0, stopped = 0;
        for (int l = 1; l <= maxLev; ++l) {
            int c = cnts[l];
            if (!stopped) { if (c > CUTN) cut = l; else stopped = 1; }
            cnts[l] = acc;
            acc += c;
            levelStart[l] = acc;
        }
        numLevels[0] = maxLev;
        numLevels[1] = cut;
    }
    __syncthreads();
    for (int t = tid; t < T_STEPS; t += 1024) {
        int pos = atomicAdd(&cnts[lev[t]], 1);
        order[pos] = t;
        levArr[t] = (int)lev[t];
    }
}

// fused transpose of all 6 matrices into [k/4][512][4] layout
__global__ void k_trans(const float* __restrict__ Uz, const float* __restrict__ Ur,
                        const float* __restrict__ Uh, const float* __restrict__ Wz,
                        const float* __restrict__ Wr, const float* __restrict__ Wh,
                        float* UzT, float* UrT, float* UhT,
                        float* WzT, float* WrT, float* WhT) {
    int y = blockIdx.y;
    int idx = blockIdx.x * blockDim.x + threadIdx.x;
    if (y < 3) {
        const float* S = (y == 0) ? Uz : (y == 1) ? Ur : Uh;
        float*       D = (y == 0) ? UzT : (y == 1) ? UrT : UhT;
        if (idx < S2 * S2) {
            int i2 = idx / S2, k = idx % S2;
            D[((k >> 2) * S2 + i2) * 4 + (k & 3)] = S[idx];
        }
    } else {
        const float* S = (y == 3) ? Wz : (y == 4) ? Wr : Wh;
        float*       D = (y == 3) ? WzT : (y == 4) ? WrT : WhT;
        if (idx < S2 * SIT) {
            int i2 = idx / SIT, k = idx % SIT;
            D[((k >> 2) * S2 + i2) * 4 + (k & 3)] = S[idx];
        }
    }
}

__global__ void k_copy(const float4* __restrict__ src, float4* dst, int n4) {
    int i = blockIdx.x * blockDim.x + threadIdx.x;
    if (i < n4) dst[i] = src[i];
}

// XP = W@x + bias for all steps (non-cooperative; one 16-step tile per block)
__global__ __launch_bounds__(512) void k_xp(
    const float* __restrict__ x,
    const float* __restrict__ WzT, const float* __restrict__ WrT, const float* __restrict__ WhT,
    const float* __restrict__ bz, const float* __restrict__ br, const float* __restrict__ bh,
    float* __restrict__ XPz, float* __restrict__ XPr, float* __restrict__ XPh)
{
    __shared__ float xs[16][SIT];
    const int i = threadIdx.x;
    const int tile = blockIdx.x;
    const float4* Wz4 = (const float4*)WzT;
    const float4* Wr4 = (const float4*)WrT;
    const float4* Wh4 = (const float4*)WhT;
    const float bzi = bz[i], bri = br[i], bhi = bh[i];

    for (int idx = i; idx < 16 * SIT; idx += 512) {
        int j = idx >> 6, k = idx & (SIT - 1);
        xs[j][k] = x[(tile * 16 + j) * SIT + k];
    }
    __syncthreads();
    float za[16], ra[16], ha[16];
#pragma unroll
    for (int j = 0; j < 16; ++j) { za[j] = 0.f; ra[j] = 0.f; ha[j] = 0.f; }
    for (int kb = 0; kb < WKB; ++kb) {
        float4 wz = Wz4[kb * S2 + i];
        float4 wr = Wr4[kb * S2 + i];
        float4 wh = Wh4[kb * S2 + i];
#pragma unroll
        for (int j = 0; j < 16; ++j) {
            float4 x4 = *(const float4*)(&xs[j][kb * 4]);
            za[j] += dot4_(wz, x4);
            ra[j] += dot4_(wr, x4);
            ha[j] += dot4_(wh, x4);
        }
    }
#pragma unroll
    for (int j = 0; j < 16; ++j) {
        int t = tile * 16 + j;
        XPz[t * S2 + i] = za[j] + bzi;
        XPr[t * S2 + i] = ra[j] - bri;
        XPh[t * S2 + i] = ha[j] + bhi;
    }
}

// ---------------- main cooperative kernel ----------------

// Phase A: R4 semantics (plain loads/stores; grid.sync provides coherence),
// with 2-ahead named-register pipeline on the U k-loops.
template<int BQ>
__device__ __forceinline__ void process_level(
    int s0, int s1, int i, int useXP,
    const float* __restrict__ x,
    const int* __restrict__ bArr, const int* __restrict__ pArr,
    const float4* __restrict__ Wz4, const float4* __restrict__ Wr4, const float4* __restrict__ Wh4,
    const float4* __restrict__ Uz4, const float4* __restrict__ Ur4, const float4* __restrict__ Uh4,
    const float* __restrict__ XPz, const float* __restrict__ XPr, const float* __restrict__ XPh,
    float bzi, float bri, float bhi,
    float* __restrict__ out, const int* __restrict__ order,
    float (*Hs)[S2], float (*RHs)[S2], float (*xs)[SIT],
    int* tj, int* rbs, int* rps)
{
    const int nT = (s1 - s0 + BQ - 1) / BQ;
    for (int tile = blockIdx.x; tile < nT; tile += gridDim.x) {
        const int sbase = s0 + tile * BQ;
        const int B = (sbase + BQ <= s1) ? BQ : (s1 - sbase);
        __syncthreads();
        if (i < BQ) {
            int t = (i < B) ? order[sbase + i] : -1;
            tj[i] = t;
            rbs[i] = (t >= 0) ? bArr[t] : 0;
            rps[i] = (t >= 0) ? pArr[t] : 0;
        }
        __syncthreads();

        for (int idx = i; idx < BQ * S2; idx += 512) {
            int j = idx >> 9, k = idx & (S2 - 1);
            float v = 0.0f;
            if (tj[j] >= 0) {
                int row = (k < SS) ? rbs[j] : rps[j];
                v = out[row * SS + (k & (SS - 1))];
            }
            Hs[j][k] = v;
        }
        if (!useXP) {
            for (int idx = i; idx < BQ * SIT; idx += 512) {
                int j = idx >> 6, k = idx & (SIT - 1);
                int t = tj[j];
                xs[j][k] = (t >= 0) ? x[t * SIT + k] : 0.0f;
            }
        }
        float zacc[BQ], racc[BQ];
        if (useXP) {
#pragma unroll
            for (int j = 0; j < BQ; ++j) {
                int t = tj[j];
                zacc[j] = (t >= 0) ? XPz[t * S2 + i] : 0.0f;
                racc[j] = (t >= 0) ? XPr[t * S2 + i] : 0.0f;
            }
        } else {
#pragma unroll
            for (int j = 0; j < BQ; ++j) { zacc[j] = 0.0f; racc[j] = 0.0f; }
        }
        __syncthreads();

        if (!useXP) {
            for (int kb = 0; kb < WKB; ++kb) {
                float4 a4 = Wz4[kb * S2 + i];
                float4 b4 = Wr4[kb * S2 + i];
#pragma unroll
                for (int j = 0; j < BQ; ++j) {
                    float4 x4 = *(const float4*)(&xs[j][kb * 4]);
                    zacc[j] += dot4_(a4, x4);
                    racc[j] += dot4_(b4, x4);
                }
            }
        }
        // U z/r loop: 2-ahead pipeline, NAMED registers (no arrays -> no scratch)
        {
            float4 az0 = Uz4[i],      ar0 = Ur4[i];
            float4 az1 = Uz4[S2 + i], ar1 = Ur4[S2 + i];
#pragma unroll 1
            for (int kb = 0; kb < NKB; ++kb) {
                int kn = kb + 2; if (kn >= NKB) kn -= NKB;
                float4 azn = Uz4[kn * S2 + i];
                float4 arn = Ur4[kn * S2 + i];
#pragma unroll
                for (int j = 0; j < BQ; ++j) {
                    float4 h4 = *(const float4*)(&Hs[j][kb * 4]);
                    zacc[j] += dot4_(az0, h4);
                    racc[j] += dot4_(ar0, h4);
                }
                az0 = az1; ar0 = ar1; az1 = azn; ar1 = arn;
            }
        }
        float zv[BQ];
#pragma unroll
        for (int j = 0; j < BQ; ++j) {
            zv[j] = sigmoidf_(useXP ? zacc[j] : (zacc[j] + bzi));
            float rv = sigmoidf_(useXP ? racc[j] : (racc[j] - bri));
            RHs[j][i] = rv * Hs[j][i];
        }
        __syncthreads();

        float macc[BQ];
        if (useXP) {
#pragma unroll
            for (int j = 0; j < BQ; ++j) {
                int t = tj[j];
                macc[j] = (t >= 0) ? XPh[t * S2 + i] : 0.0f;
            }
        } else {
#pragma unroll
            for (int j = 0; j < BQ; ++j) macc[j] = 0.0f;
            for (int kb = 0; kb < WKB; ++kb) {
                float4 a4 = Wh4[kb * S2 + i];
#pragma unroll
                for (int j = 0; j < BQ; ++j) {
                    float4 x4 = *(const float4*)(&xs[j][kb * 4]);
                    macc[j] += dot4_(a4, x4);
                }
            }
        }
        {
            float4 ah0 = Uh4[i];
            float4 ah1 = Uh4[S2 + i];
#pragma unroll 1
            for (int kb = 0; kb < NKB; ++kb) {
                int kn = kb + 2; if (kn >= NKB) kn -= NKB;
                float4 ahn = Uh4[kn * S2 + i];
#pragma unroll
                for (int j = 0; j < BQ; ++j) {
                    float4 h4 = *(const float4*)(&RHs[j][kb * 4]);
                    macc[j] += dot4_(ah0, h4);
                }
                ah0 = ah1; ah1 = ahn;
            }
        }
        for (int j = 0; j < B; ++j) {
            float mm = tanhf(useXP ? macc[j] : (macc[j] + bhi));
            float h = Hs[j][i];
            float hn = zv[j] * h + (1.0f - zv[j]) * mm;
            int rb = rbs[j], rp = rps[j];
            int row = (i < SS) ? rb : rp;
            float* addr = out + row * SS + (i & (SS - 1));
            if (rb == rp) atomicAdd(addr, hn - h);
            else *addr = hn;
        }
    }
}

__global__ __launch_bounds__(512, 4) void k_main(
    const float* __restrict__ x, const int* __restrict__ bArr, const int* __restrict__ pArr,
    const float* __restrict__ WzT, const float* __restrict__ WrT, const float* __restrict__ WhT,
    const float* __restrict__ UzT, const float* __restrict__ UrT, const float* __restrict__ UhT,
    const float* __restrict__ bz, const float* __restrict__ br, const float* __restrict__ bh,
    float* __restrict__ out,
    const int* __restrict__ order, const int* __restrict__ levelStart,
    const int* __restrict__ numLevels,
    const float* __restrict__ XPz, const float* __restrict__ XPr, const float* __restrict__ XPh,
    const int* __restrict__ pred, const int* __restrict__ levArr, int* __restrict__ flagArr,
    int useXP)
{
    cg::grid_group grid = cg::this_grid();
    __shared__ float Hs[BQMAX][S2];
    __shared__ float RHs[BQMAX][S2];
    __shared__ float xs[BQMAX][SIT];
    __shared__ int tj[BQMAX], rbs[BQMAX], rps[BQMAX];

    const int i = threadIdx.x;
    const float bzi = bz[i], bri = br[i], bhi = bh[i];
    const float4* Uz4 = (const float4*)UzT;
    const float4* Ur4 = (const float4*)UrT;
    const float4* Uh4 = (const float4*)UhT;
    const float4* Wz4 = (const float4*)WzT;
    const float4* Wr4 = (const float4*)WrT;
    const float4* Wh4 = (const float4*)WhT;

    const int cutoff = numLevels[1];

    // ---- phase A: big levels, tile mode ----
    for (int lvl = 1; lvl <= cutoff; ++lvl) {
        const int s0 = levelStart[lvl - 1], s1 = levelStart[lvl];
        const int n = s1 - s0;
        if (n > 3000)
            process_level<16>(s0, s1, i, useXP, x, bArr, pArr, Wz4, Wr4, Wh4,
                              Uz4, Ur4, Uh4, XPz, XPr, XPh, bzi, bri, bhi,
                              out, order, Hs, RHs, xs, tj, rbs, rps);
        else if (n > 1000)
            process_level<8>(s0, s1, i, useXP, x, bArr, pArr, Wz4, Wr4, Wh4,
                             Uz4, Ur4, Uh4, XPz, XPr, XPh, bzi, bri, bhi,
                             out, order, Hs, RHs, xs, tj, rbs, rps);
        else
            process_level<4>(s0, s1, i, useXP, x, bArr, pArr, Wz4, Wr4, Wh4,
                             Uz4, Ur4, Uh4, XPz, XPr, XPh, bzi, bri, bhi,
                             out, order, Hs, RHs, xs, tj, rbs, rps);
        grid.sync();
    }

    const int sB = levelStart[cutoff];    // first phase-B position in order[]

    // ---- init flags: phase-A steps done, phase-B steps pending ----
    for (int s = blockIdx.x * 512 + i; s < T_STEPS; s += gridDim.x * 512)
        flagArr[order[s]] = (s < sB) ? 1 : 0;
    grid.sync();

    // ---- phase B: dataflow chain mode (level-sorted assignment, no grid.sync) ----
    float* Hs0 = &Hs[0][0];
    float* RHs0 = &RHs[0][0];
    float* xs0 = &xs[0][0];
    for (int s = sB + blockIdx.x; s < T_STEPS; s += gridDim.x) {
        const int t = order[s];
        // wait for predecessors (thread 0 spins; acquire orders subsequent reads)
        if (i == 0) {
            int p0 = pred[2 * t], p1 = pred[2 * t + 1];
            while (p0 >= 0 && __hip_atomic_load(&flagArr[p0], __ATOMIC_ACQUIRE,
                                                __HIP_MEMORY_SCOPE_AGENT) == 0)
                __builtin_amdgcn_s_sleep(2);
            while (p1 >= 0 && __hip_atomic_load(&flagArr[p1], __ATOMIC_ACQUIRE,
                                                __HIP_MEMORY_SCOPE_AGENT) == 0)
                __builtin_amdgcn_s_sleep(2);
        }
        __syncthreads();

        const int rb = bArr[t], rp = pArr[t];
        const int row = (i < SS) ? rb : rp;
        float* addr = out + row * SS + (i & (SS - 1));
        const float h = loadLLC_(addr);
        Hs0[i] = h;
        float zacc, racc;
        if (useXP) {
            zacc = XPz[t * S2 + i];
            racc = XPr[t * S2 + i];
        } else {
            zacc = 0.0f; racc = 0.0f;
            if (i < SIT) xs0[i] = x[t * SIT + i];
        }
        __syncthreads();

        if (!useXP) {
            for (int kb = 0; kb < WKB; ++kb) {
                float4 a4 = Wz4[kb * S2 + i];
                float4 b4 = Wr4[kb * S2 + i];
                float4 x4 = *(const float4*)(&xs0[kb * 4]);
                zacc += dot4_(a4, x4);
                racc += dot4_(b4, x4);
            }
        }
        {   // 4-ahead pipeline, named registers
            float4 az0 = Uz4[i],           ar0 = Ur4[i];
            float4 az1 = Uz4[S2 + i],      ar1 = Ur4[S2 + i];
            float4 az2 = Uz4[2 * S2 + i],  ar2 = Ur4[2 * S2 + i];
            float4 az3 = Uz4[3 * S2 + i],  ar3 = Ur4[3 * S2 + i];
#pragma unroll 1
            for (int kb = 0; kb < NKB; ++kb) {
                int kn = kb + 4; if (kn >= NKB) kn -= NKB;
                float4 azn = Uz4[kn * S2 + i];
                float4 arn = Ur4[kn * S2 + i];
                float4 h4 = *(const float4*)(&Hs0[kb * 4]);
                zacc += dot4_(az0, h4);
                racc += dot4_(ar0, h4);
                az0 = az1; ar0 = ar1; az1 = az2; ar1 = ar2;
                az2 = az3; ar2 = ar3; az3 = azn; ar3 = arn;
            }
        }
        const float zv = sigmoidf_(useXP ? zacc : (zacc + bzi));
        const float rv = sigmoidf_(useXP ? racc : (racc - bri));
        RHs0[i] = rv * h;
        __syncthreads();

        float macc;
        if (useXP) {
            macc = XPh[t * S2 + i];
        } else {
            macc = 0.0f;
            for (int kb = 0; kb < WKB; ++kb) {
                float4 a4 = Wh4[kb * S2 + i];
                float4 x4 = *(const float4*)(&xs0[kb * 4]);
                macc += dot4_(a4, x4);
            }
        }
        {   // 4-ahead pipeline, named registers
            float4 ah0 = Uh4[i];
            float4 ah1 = Uh4[S2 + i];
            float4 ah2 = Uh4[2 * S2 + i];
            float4 ah3 = Uh4[3 * S2 + i];
#pragma unroll 1
            for (int kb = 0; kb < NKB; ++kb) {
                int kn = kb + 4; if (kn >= NKB) kn -= NKB;
                float4 ahn = Uh4[kn * S2 + i];
                float4 h4 = *(const float4*)(&RHs0[kb * 4]);
                macc += dot4_(ah0, h4);
                ah0 = ah1; ah1 = ah2; ah2 = ah3; ah3 = ahn;
            }
        }
        const float mm = tanhf(useXP ? macc : (macc + bhi));
        const float hn = zv * h + (1.0f - zv) * mm;
        if (rb == rp) atomicAdd(addr, hn - h);
        else storeLLC_(addr, hn);
        __syncthreads();   // all lanes' stores drained (waitcnt before barrier)
        if (i == 0)
            __hip_atomic_store(&flagArr[t], 1, __ATOMIC_RELEASE, __HIP_MEMORY_SCOPE_AGENT);
    }
}

// ---------------- host launcher ----------------

extern "C" void kernel_launch(void* const* d_in, const int* in_sizes, int n_in,
                              void* d_out, int out_size, void* d_ws, size_t ws_size,
                              hipStream_t stream) {
    const float* x  = (const float*)d_in[0];
    const int*   b  = (const int*)d_in[1];
    const int*   p  = (const int*)d_in[2];
    const float* Wz = (const float*)d_in[3];
    const float* Wr = (const float*)d_in[4];
    const float* Wh = (const float*)d_in[5];
    const float* Uz = (const float*)d_in[6];
    const float* Ur = (const float*)d_in[7];
    const float* Uh = (const float*)d_in[8];
    const float* bz = (const float*)d_in[9];
    const float* br = (const float*)d_in[10];
    const float* bh = (const float*)d_in[11];
    const float* table0 = (const float*)d_in[12];
    float* out = (float*)d_out;

    float* UzT = (float*)d_ws;
    float* UrT = UzT + S2 * S2;
    float* UhT = UrT + S2 * S2;
    float* WzT = UhT + S2 * S2;
    float* WrT = WzT + S2 * SIT;
    float* WhT = WrT + S2 * SIT;
    int* cnt = (int*)(WhT + S2 * SIT);
    int* cur = cnt + NPL;
    int* bas = cur + NPL;
    int* list = bas + NPL;
    int* pred = list + NEV;
    int* order = pred + NEV;
    int* levelStart = order + T_STEPS;
    int* numLevels = levelStart + 260;   // [0]=maxLev, [1]=cutoff (+2 pad)
    int* levArr = numLevels + 4;
    int* flagArr = levArr + T_STEPS;

    size_t baseFloats = (size_t)(3 * S2 * S2 + 3 * S2 * SIT)
                      + 3 * NPL + 2 * NEV + 3 * T_STEPS + 264;
    baseFloats = (baseFloats + 255) & ~(size_t)255;
    float* XPz = (float*)d_ws + baseFloats;
    float* XPr = XPz + (size_t)T_STEPS * S2;
    float* XPh = XPr + (size_t)T_STEPS * S2;
    size_t needBytes = (baseFloats + 3ull * T_STEPS * S2) * 4ull;
    int useXP = (ws_size >= needBytes) ? 1 : 0;

    hipLaunchKernelGGL(k_trans, dim3(1024, 6), dim3(256), 0, stream,
                       Uz, Ur, Uh, Wz, Wr, Wh, UzT, UrT, UhT, WzT, WrT, WhT);
    hipLaunchKernelGGL(k_zero, dim3((NPL + 255) / 256), dim3(256), 0, stream, cnt);
    hipLaunchKernelGGL(k_count, dim3((NEV + 255) / 256), dim3(256), 0, stream, b, p, cnt);
    hipLaunchKernelGGL(k_scan, dim3(1), dim3(1024), 0, stream, cnt, bas, cur);
    hipLaunchKernelGGL(k_place, dim3((NEV + 255) / 256), dim3(256), 0, stream, b, p, cur, list);
    hipLaunchKernelGGL(k_pred, dim3((NPL + 255) / 256), dim3(256), 0, stream, bas, cnt, list, pred);
    hipLaunchKernelGGL(k_levels, dim3(1), dim3(1024), 0, stream,
                       pred, order, levelStart, numLevels, levArr);

    int n4 = NPL * SS / 4;
    hipLaunchKernelGGL(k_copy, dim3((n4 + 255) / 256), dim3(256), 0, stream,
                       (const float4*)table0, (float4*)out, n4);
    if (useXP) {
        hipLaunchKernelGGL(k_xp, dim3(T_STEPS / 16), dim3(512), 0, stream,
                           x, WzT, WrT, WhT, bz, br, bh, XPz, XPr, XPh);
    }

    // grid sizing: query capacity, clamp DOWN only (never exceed what fits)
    int occ = 0;
    if (hipOccupancyMaxActiveBlocksPerMultiprocessor(&occ, k_main, 512, 0) != hipSuccess)
        occ = 1;
    if (occ < 1) occ = 1;
    if (occ > 2) occ = 2;
    int gridSz = occ * 256;

    void* args[] = {
        (void*)&x, (void*)&b, (void*)&p,
        (void*)&WzT, (void*)&WrT, (void*)&WhT,
        (void*)&UzT, (void*)&UrT, (void*)&UhT,
        (void*)&bz, (void*)&br, (void*)&bh,
        (void*)&out,
        (void*)&order, (void*)&levelStart, (void*)&numLevels,
        (void*)&XPz, (void*)&XPr, (void*)&XPh,
        (void*)&pred, (void*)&levArr, (void*)&flagArr, (void*)&useXP
    };
    hipError_t e = hipLaunchCooperativeKernel((void*)k_main, dim3(gridSz), dim3(512), args, 0, stream);
    if (e != hipSuccess && gridSz != 256) {
        hipLaunchCooperativeKernel((void*)k_main, dim3(256), dim3(512), args, 0, stream);
    }
}

// Round 10
// 1068.161 us; speedup vs baseline: 2.6779x; 1.0599x over previous
//
#include <hip/hip_runtime.h>
#include <hip/hip_cooperative_groups.h>

namespace cg = cooperative_groups;

#define T_STEPS 8192
#define SIT     64
#define SS      256
#define S2      512
#define NPL     32000
#define NEV     (2*T_STEPS)
#define MAXLEV  255
#define RELAX   48
#define NKB     (S2/4)    // 128 k-blocks for U part
#define WKB     (SIT/4)   // 16 k-blocks for W part
#define BQMAX   16
#define CUTN    300       // levels larger than this run in phase A (tile mode)
#define NSLICE  4
#define MAXB    4096      // max phase-B steps supported by sliced mode

__device__ __forceinline__ float sigmoidf_(float x) {
    return 1.0f / (1.0f + expf(-x));
}
__device__ __forceinline__ float dot4_(float4 a, float4 b) {
    return a.x*b.x + a.y*b.y + a.z*b.z + a.w*b.w;
}
__device__ __forceinline__ float loadLLC_(const float* p) {
    return __hip_atomic_load(p, __ATOMIC_RELAXED, __HIP_MEMORY_SCOPE_AGENT);
}
__device__ __forceinline__ void storeLLC_(float* p, float v) {
    __hip_atomic_store(p, v, __ATOMIC_RELAXED, __HIP_MEMORY_SCOPE_AGENT);
}

// ---------------- preprocessing kernels ----------------

__global__ void k_zero(int* cnt) {
    int i = blockIdx.x * blockDim.x + threadIdx.x;
    if (i < NPL) cnt[i] = 0;
}

__global__ void k_count(const int* __restrict__ b, const int* __restrict__ p, int* cnt) {
    int e = blockIdx.x * blockDim.x + threadIdx.x;
    if (e < NEV) {
        int v = (e & 1) ? p[e >> 1] : b[e >> 1];
        atomicAdd(&cnt[v], 1);
    }
}

__global__ __launch_bounds__(1024) void k_scan(const int* __restrict__ cnt, int* bas, int* cur) {
    __shared__ int partial[1024];
    int tid = threadIdx.x;
    int start = tid * 32;
    int end = start + 32; if (end > NPL) end = NPL;
    int s = 0;
    for (int i = start; i < end; ++i) s += cnt[i];
    partial[tid] = s;
    __syncthreads();
    for (int off = 1; off < 1024; off <<= 1) {
        int v = partial[tid];
        int add = (tid >= off) ? partial[tid - off] : 0;
        __syncthreads();
        partial[tid] = v + add;
        __syncthreads();
    }
    int acc = (tid == 0) ? 0 : partial[tid - 1];
    for (int i = start; i < end; ++i) {
        bas[i] = acc; cur[i] = acc; acc += cnt[i];
    }
}

__global__ void k_place(const int* __restrict__ b, const int* __restrict__ p, int* cur, int* list) {
    int e = blockIdx.x * blockDim.x + threadIdx.x;
    if (e < NEV) {
        int v = (e & 1) ? p[e >> 1] : b[e >> 1];
        int pos = atomicAdd(&cur[v], 1);
        list[pos] = e;
    }
}

__global__ void k_pred(const int* __restrict__ bas, const int* __restrict__ cnt, int* list, int* pred) {
    int v = blockIdx.x * blockDim.x + threadIdx.x;
    if (v >= NPL) return;
    int s0 = bas[v], c = cnt[v];
    for (int i2 = 1; i2 < c; ++i2) {
        int key = list[s0 + i2];
        int j = i2 - 1;
        while (j >= 0 && list[s0 + j] > key) { list[s0 + j + 1] = list[s0 + j]; --j; }
        list[s0 + j + 1] = key;
    }
    int prevS = -1, curS = -1;
    for (int i2 = 0; i2 < c; ++i2) {
        int e = list[s0 + i2];
        int s = e >> 1;
        if (s != curS) { prevS = curS; curS = s; }
        pred[e] = prevS;
    }
}

__global__ __launch_bounds__(1024) void k_levels(const int* __restrict__ pred,
                                                 int* order, int* levelStart, int* numLevels) {
    __shared__ short p0[T_STEPS], p1[T_STEPS];
    __shared__ unsigned char lev[T_STEPS];
    __shared__ int cnts[MAXLEV + 2];
    __shared__ int maxLev;
    __shared__ int changed;
    int tid = threadIdx.x;
    for (int t = tid; t < T_STEPS; t += 1024) {
        p0[t] = (short)pred[2 * t];
        p1[t] = (short)pred[2 * t + 1];
        lev[t] = 1;
    }
    for (int l = tid; l < MAXLEV + 2; l += 1024) cnts[l] = 0;
    if (tid == 0) maxLev = 0;
    __syncthreads();
    for (int r = 0; r < RELAX; ++r) {
        if (tid == 0) changed = 0;
        __syncthreads();
        for (int t = tid; t < T_STEPS; t += 1024) {
            int a = p0[t], b2 = p1[t];
            int la = (a >= 0) ? (int)lev[a] : 0;
            int lb = (b2 >= 0) ? (int)lev[b2] : 0;
            int nl = 1 + (la > lb ? la : lb);
            if (nl > MAXLEV) nl = MAXLEV;
            if (nl > (int)lev[t]) { lev[t] = (unsigned char)nl; changed = 1; }
        }
        __syncthreads();
        int ch = changed;
        __syncthreads();
        if (!ch) break;
    }
    for (int t = tid; t < T_STEPS; t += 1024) {
        atomicAdd(&cnts[lev[t]], 1);
        atomicMax(&maxLev, (int)lev[t]);
    }
    __syncthreads();
    if (tid == 0) {
        int acc = 0;
        levelStart[0] = 0;
        int cut = 0, stopped = 0;
        for (int l = 1; l <= maxLev; ++l) {
            int c = cnts[l];
            if (!stopped) { if (c > CUTN) cut = l; else stopped = 1; }
            cnts[l] = acc;
            acc += c;
            levelStart[l] = acc;
        }
        numLevels[0] = maxLev;
        numLevels[1] = cut;
    }
    __syncthreads();
    for (int t = tid; t < T_STEPS; t += 1024) {
        int pos = atomicAdd(&cnts[lev[t]], 1);
        order[pos] = t;
    }
}

// fused transpose of all 6 matrices into [k/4][512][4] layout
__global__ void k_trans(const float* __restrict__ Uz, const float* __restrict__ Ur,
                        const float* __restrict__ Uh, const float* __restrict__ Wz,
                        const float* __restrict__ Wr, const float* __restrict__ Wh,
                        float* UzT, float* UrT, float* UhT,
                        float* WzT, float* WrT, float* WhT) {
    int y = blockIdx.y;
    int idx = blockIdx.x * blockDim.x + threadIdx.x;
    if (y < 3) {
        const float* S = (y == 0) ? Uz : (y == 1) ? Ur : Uh;
        float*       D = (y == 0) ? UzT : (y == 1) ? UrT : UhT;
        if (idx < S2 * S2) {
            int i2 = idx / S2, k = idx % S2;
            D[((k >> 2) * S2 + i2) * 4 + (k & 3)] = S[idx];
        }
    } else {
        const float* S = (y == 3) ? Wz : (y == 4) ? Wr : Wh;
        float*       D = (y == 3) ? WzT : (y == 4) ? WrT : WhT;
        if (idx < S2 * SIT) {
            int i2 = idx / SIT, k = idx % SIT;
            D[((k >> 2) * S2 + i2) * 4 + (k & 3)] = S[idx];
        }
    }
}

__global__ void k_copy(const float4* __restrict__ src, float4* dst, int n4) {
    int i = blockIdx.x * blockDim.x + threadIdx.x;
    if (i < n4) dst[i] = src[i];
}

// XP = W@x + bias for all steps
__global__ __launch_bounds__(512) void k_xp(
    const float* __restrict__ x,
    const float* __restrict__ WzT, const float* __restrict__ WrT, const float* __restrict__ WhT,
    const float* __restrict__ bz, const float* __restrict__ br, const float* __restrict__ bh,
    float* __restrict__ XPz, float* __restrict__ XPr, float* __restrict__ XPh)
{
    __shared__ float xs[16][SIT];
    const int i = threadIdx.x;
    const int tile = blockIdx.x;
    const float4* Wz4 = (const float4*)WzT;
    const float4* Wr4 = (const float4*)WrT;
    const float4* Wh4 = (const float4*)WhT;
    const float bzi = bz[i], bri = br[i], bhi = bh[i];

    for (int idx = i; idx < 16 * SIT; idx += 512) {
        int j = idx >> 6, k = idx & (SIT - 1);
        xs[j][k] = x[(tile * 16 + j) * SIT + k];
    }
    __syncthreads();
    float za[16], ra[16], ha[16];
#pragma unroll
    for (int j = 0; j < 16; ++j) { za[j] = 0.f; ra[j] = 0.f; ha[j] = 0.f; }
    for (int kb = 0; kb < WKB; ++kb) {
        float4 wz = Wz4[kb * S2 + i];
        float4 wr = Wr4[kb * S2 + i];
        float4 wh = Wh4[kb * S2 + i];
#pragma unroll
        for (int j = 0; j < 16; ++j) {
            float4 x4 = *(const float4*)(&xs[j][kb * 4]);
            za[j] += dot4_(wz, x4);
            ra[j] += dot4_(wr, x4);
            ha[j] += dot4_(wh, x4);
        }
    }
#pragma unroll
    for (int j = 0; j < 16; ++j) {
        int t = tile * 16 + j;
        XPz[t * S2 + i] = za[j] + bzi;
        XPr[t * S2 + i] = ra[j] - bri;
        XPh[t * S2 + i] = ha[j] + bhi;
    }
}

// ---------------- main cooperative kernel ----------------

// Phase A: R4-proven simple tile body.
template<int BQ>
__device__ __forceinline__ void process_level(
    int s0, int s1, int i, int useXP,
    const float* __restrict__ x,
    const int* __restrict__ bArr, const int* __restrict__ pArr,
    const float4* __restrict__ Wz4, const float4* __restrict__ Wr4, const float4* __restrict__ Wh4,
    const float4* __restrict__ Uz4, const float4* __restrict__ Ur4, const float4* __restrict__ Uh4,
    const float* __restrict__ XPz, const float* __restrict__ XPr, const float* __restrict__ XPh,
    float bzi, float bri, float bhi,
    float* __restrict__ out, const int* __restrict__ order,
    float (*Hs)[S2], float (*RHs)[S2], float (*xs)[SIT],
    int* tj, int* rbs, int* rps)
{
    const int nT = (s1 - s0 + BQ - 1) / BQ;
    for (int tile = blockIdx.x; tile < nT; tile += gridDim.x) {
        const int sbase = s0 + tile * BQ;
        const int B = (sbase + BQ <= s1) ? BQ : (s1 - sbase);
        __syncthreads();
        if (i < BQ) {
            int t = (i < B) ? order[sbase + i] : -1;
            tj[i] = t;
            rbs[i] = (t >= 0) ? bArr[t] : 0;
            rps[i] = (t >= 0) ? pArr[t] : 0;
        }
        __syncthreads();

        for (int idx = i; idx < BQ * S2; idx += 512) {
            int j = idx >> 9, k = idx & (S2 - 1);
            float v = 0.0f;
            if (tj[j] >= 0) {
                int row = (k < SS) ? rbs[j] : rps[j];
                v = out[row * SS + (k & (SS - 1))];
            }
            Hs[j][k] = v;
        }
        if (!useXP) {
            for (int idx = i; idx < BQ * SIT; idx += 512) {
                int j = idx >> 6, k = idx & (SIT - 1);
                int t = tj[j];
                xs[j][k] = (t >= 0) ? x[t * SIT + k] : 0.0f;
            }
        }
        float zacc[BQ], racc[BQ];
        if (useXP) {
#pragma unroll
            for (int j = 0; j < BQ; ++j) {
                int t = tj[j];
                zacc[j] = (t >= 0) ? XPz[t * S2 + i] : 0.0f;
                racc[j] = (t >= 0) ? XPr[t * S2 + i] : 0.0f;
            }
        } else {
#pragma unroll
            for (int j = 0; j < BQ; ++j) { zacc[j] = 0.0f; racc[j] = 0.0f; }
        }
        __syncthreads();

        if (!useXP) {
            for (int kb = 0; kb < WKB; ++kb) {
                float4 a4 = Wz4[kb * S2 + i];
                float4 b4 = Wr4[kb * S2 + i];
#pragma unroll
                for (int j = 0; j < BQ; ++j) {
                    float4 x4 = *(const float4*)(&xs[j][kb * 4]);
                    zacc[j] += dot4_(a4, x4);
                    racc[j] += dot4_(b4, x4);
                }
            }
        }
        for (int kb = 0; kb < NKB; ++kb) {
            float4 a4 = Uz4[kb * S2 + i];
            float4 b4 = Ur4[kb * S2 + i];
#pragma unroll
            for (int j = 0; j < BQ; ++j) {
                float4 h4 = *(const float4*)(&Hs[j][kb * 4]);
                zacc[j] += dot4_(a4, h4);
                racc[j] += dot4_(b4, h4);
            }
        }
        float zv[BQ];
#pragma unroll
        for (int j = 0; j < BQ; ++j) {
            zv[j] = sigmoidf_(useXP ? zacc[j] : (zacc[j] + bzi));
            float rv = sigmoidf_(useXP ? racc[j] : (racc[j] - bri));
            RHs[j][i] = rv * Hs[j][i];
        }
        __syncthreads();

        float macc[BQ];
        if (useXP) {
#pragma unroll
            for (int j = 0; j < BQ; ++j) {
                int t = tj[j];
                macc[j] = (t >= 0) ? XPh[t * S2 + i] : 0.0f;
            }
        } else {
#pragma unroll
            for (int j = 0; j < BQ; ++j) macc[j] = 0.0f;
            for (int kb = 0; kb < WKB; ++kb) {
                float4 a4 = Wh4[kb * S2 + i];
#pragma unroll
                for (int j = 0; j < BQ; ++j) {
                    float4 x4 = *(const float4*)(&xs[j][kb * 4]);
                    macc[j] += dot4_(a4, x4);
                }
            }
        }
        for (int kb = 0; kb < NKB; ++kb) {
            float4 a4 = Uh4[kb * S2 + i];
#pragma unroll
            for (int j = 0; j < BQ; ++j) {
                float4 h4 = *(const float4*)(&RHs[j][kb * 4]);
                macc[j] += dot4_(a4, h4);
            }
        }
        for (int j = 0; j < B; ++j) {
            float mm = tanhf(useXP ? macc[j] : (macc[j] + bhi));
            float h = Hs[j][i];
            float hn = zv[j] * h + (1.0f - zv[j]) * mm;
            int rb = rbs[j], rp = rps[j];
            int row = (i < SS) ? rb : rp;
            float* addr = out + row * SS + (i & (SS - 1));
            if (rb == rp) atomicAdd(addr, hn - h);
            else *addr = hn;
        }
    }
}

__global__ __launch_bounds__(512, 4) void k_main(
    const float* __restrict__ x, const int* __restrict__ bArr, const int* __restrict__ pArr,
    const float* __restrict__ WzT, const float* __restrict__ WrT, const float* __restrict__ WhT,
    const float* __restrict__ UzT, const float* __restrict__ UrT, const float* __restrict__ UhT,
    const float* __restrict__ bz, const float* __restrict__ br, const float* __restrict__ bh,
    float* __restrict__ out,
    const int* __restrict__ order, const int* __restrict__ levelStart,
    const int* __restrict__ numLevels,
    const float* __restrict__ XPz, const float* __restrict__ XPr, const float* __restrict__ XPh,
    const int* __restrict__ pred, int* __restrict__ flagArr,
    int* __restrict__ rhCnt, float* __restrict__ RHstage,
    int useXP, int useSlice)
{
    cg::grid_group grid = cg::this_grid();
    __shared__ float Hs[BQMAX][S2];
    __shared__ float RHs[BQMAX][S2];
    __shared__ float xs[BQMAX][SIT];
    __shared__ int tj[BQMAX], rbs[BQMAX], rps[BQMAX];

    const int i = threadIdx.x;
    const float bzi = bz[i], bri = br[i], bhi = bh[i];
    const float4* Uz4 = (const float4*)UzT;
    const float4* Ur4 = (const float4*)UrT;
    const float4* Uh4 = (const float4*)UhT;
    const float4* Wz4 = (const float4*)WzT;
    const float4* Wr4 = (const float4*)WrT;
    const float4* Wh4 = (const float4*)WhT;

    const int cutoff = numLevels[1];

    // ---- phase A: big levels, tile mode ----
    for (int lvl = 1; lvl <= cutoff; ++lvl) {
        const int s0 = levelStart[lvl - 1], s1 = levelStart[lvl];
        const int n = s1 - s0;
        if (n > 3000)
            process_level<16>(s0, s1, i, useXP, x, bArr, pArr, Wz4, Wr4, Wh4,
                              Uz4, Ur4, Uh4, XPz, XPr, XPh, bzi, bri, bhi,
                              out, order, Hs, RHs, xs, tj, rbs, rps);
        else if (n > 1000)
            process_level<8>(s0, s1, i, useXP, x, bArr, pArr, Wz4, Wr4, Wh4,
                             Uz4, Ur4, Uh4, XPz, XPr, XPh, bzi, bri, bhi,
                             out, order, Hs, RHs, xs, tj, rbs, rps);
        else
            process_level<4>(s0, s1, i, useXP, x, bArr, pArr, Wz4, Wr4, Wh4,
                             Uz4, Ur4, Uh4, XPz, XPr, XPh, bzi, bri, bhi,
                             out, order, Hs, RHs, xs, tj, rbs, rps);
        grid.sync();
    }

    const int sB = levelStart[cutoff];    // first phase-B position in order[]
    const int nB = T_STEPS - sB;

    // ---- init flags/counters ----
    for (int s = blockIdx.x * 512 + i; s < T_STEPS; s += gridDim.x * 512)
        flagArr[order[s]] = (s < sB) ? NSLICE : 0;
    for (int c = blockIdx.x * 512 + i; c < MAXB; c += gridDim.x * 512)
        rhCnt[c] = 0;
    grid.sync();

    float* Hs0 = &Hs[0][0];
    float* RHs0 = &RHs[0][0];
    float* xs0 = &xs[0][0];

    if (useSlice && nB <= MAXB) {
        // ---- phase B (sliced): 4 blocks per step, rows split 128 each ----
        const int jr = i & 127;           // row within slice
        const int ks = i >> 7;            // k-subrange 0..3
        for (int g = blockIdx.x; g < NSLICE * nB; g += gridDim.x) {
            const int s = sB + (g >> 2);
            const int q = g & 3;
            const int t = order[s];
            const int slot = s - sB;
            if (i == 0) {
                int p0 = pred[2 * t], p1 = pred[2 * t + 1];
                while (p0 >= 0 && __hip_atomic_load(&flagArr[p0], __ATOMIC_ACQUIRE,
                                                    __HIP_MEMORY_SCOPE_AGENT) < NSLICE)
                    __builtin_amdgcn_s_sleep(2);
                while (p1 >= 0 && __hip_atomic_load(&flagArr[p1], __ATOMIC_ACQUIRE,
                                                    __HIP_MEMORY_SCOPE_AGENT) < NSLICE)
                    __builtin_amdgcn_s_sleep(2);
            }
            __syncthreads();

            const int rb = bArr[t], rp = pArr[t];
            {
                const int row = (i < SS) ? rb : rp;
                Hs0[i] = loadLLC_(out + row * SS + (i & (SS - 1)));
            }
            __syncthreads();

            const int myrow = q * 128 + jr;
            const int kb0 = ks * 32;
            float zp = 0.f, rpv = 0.f;
            for (int kb = kb0; kb < kb0 + 32; ++kb) {
                float4 uz = Uz4[kb * S2 + myrow];
                float4 ur = Ur4[kb * S2 + myrow];
                float4 h4 = *(const float4*)(&Hs0[kb * 4]);
                zp += dot4_(uz, h4);
                rpv += dot4_(ur, h4);
            }
            RHs[1][ks * 128 + jr] = zp;
            RHs[2][ks * 128 + jr] = rpv;
            __syncthreads();
            if (i < 128) {
                float zsum = XPz[t * S2 + q * 128 + i]
                           + RHs[1][i] + RHs[1][128 + i] + RHs[1][256 + i] + RHs[1][384 + i];
                float rsum = XPr[t * S2 + q * 128 + i]
                           + RHs[2][i] + RHs[2][128 + i] + RHs[2][256 + i] + RHs[2][384 + i];
                float zv = sigmoidf_(zsum);
                float hOwn = Hs0[q * 128 + i];
                float rh = sigmoidf_(rsum) * hOwn;
                storeLLC_(RHstage + (size_t)slot * S2 + q * 128 + i, rh);
                RHs[3][i] = zv;                         // stash z for the final stage
            }
            __syncthreads();                            // drain RH stores (vmcnt) + LDS
            if (i == 0) {
                __hip_atomic_fetch_add(&rhCnt[slot], 1, __ATOMIC_RELEASE,
                                       __HIP_MEMORY_SCOPE_AGENT);
                while (__hip_atomic_load(&rhCnt[slot], __ATOMIC_ACQUIRE,
                                         __HIP_MEMORY_SCOPE_AGENT) < NSLICE)
                    __builtin_amdgcn_s_sleep(1);
            }
            __syncthreads();
            RHs0[i] = loadLLC_(RHstage + (size_t)slot * S2 + i);
            __syncthreads();

            float mp = 0.f;
            for (int kb = kb0; kb < kb0 + 32; ++kb) {
                float4 uh = Uh4[kb * S2 + myrow];
                float4 h4 = *(const float4*)(&RHs0[kb * 4]);
                mp += dot4_(uh, h4);
            }
            RHs[1][ks * 128 + jr] = mp;
            __syncthreads();
            if (i < 128) {
                float msum = XPh[t * S2 + q * 128 + i]
                           + RHs[1][i] + RHs[1][128 + i] + RHs[1][256 + i] + RHs[1][384 + i];
                float mm = tanhf(msum);
                float zz = RHs[3][i];
                float h0 = Hs0[q * 128 + i];
                float hn = zz * h0 + (1.f - zz) * mm;
                int grow = q * 128 + i;
                int orow = (grow < SS) ? rb : rp;
                float* addr = out + orow * SS + (grow & (SS - 1));
                if (rb == rp) atomicAdd(addr, hn - h0);
                else storeLLC_(addr, hn);
            }
            __syncthreads();                            // drain out stores
            if (i == 0)
                __hip_atomic_fetch_add(&flagArr[t], 1, __ATOMIC_RELEASE,
                                       __HIP_MEMORY_SCOPE_AGENT);
        }
    } else {
        // ---- phase B fallback: one block per step (R8-proven) ----
        for (int s = sB + blockIdx.x; s < T_STEPS; s += gridDim.x) {
            const int t = order[s];
            if (i == 0) {
                int p0 = pred[2 * t], p1 = pred[2 * t + 1];
                while (p0 >= 0 && __hip_atomic_load(&flagArr[p0], __ATOMIC_ACQUIRE,
                                                    __HIP_MEMORY_SCOPE_AGENT) < NSLICE)
                    __builtin_amdgcn_s_sleep(2);
                while (p1 >= 0 && __hip_atomic_load(&flagArr[p1], __ATOMIC_ACQUIRE,
                                                    __HIP_MEMORY_SCOPE_AGENT) < NSLICE)
                    __builtin_amdgcn_s_sleep(2);
            }
            __syncthreads();

            const int rb = bArr[t], rp = pArr[t];
            const int row = (i < SS) ? rb : rp;
            float* addr = out + row * SS + (i & (SS - 1));
            const float h = loadLLC_(addr);
            Hs0[i] = h;
            float zacc, racc;
            if (useXP) {
                zacc = XPz[t * S2 + i];
                racc = XPr[t * S2 + i];
            } else {
                zacc = 0.0f; racc = 0.0f;
                if (i < SIT) xs0[i] = x[t * SIT + i];
            }
            __syncthreads();

            if (!useXP) {
                for (int kb = 0; kb < WKB; ++kb) {
                    float4 a4 = Wz4[kb * S2 + i];
                    float4 b4 = Wr4[kb * S2 + i];
                    float4 x4 = *(const float4*)(&xs0[kb * 4]);
                    zacc += dot4_(a4, x4);
                    racc += dot4_(b4, x4);
                }
            }
            for (int kb = 0; kb < NKB; ++kb) {
                float4 a4 = Uz4[kb * S2 + i];
                float4 b4 = Ur4[kb * S2 + i];
                float4 h4 = *(const float4*)(&Hs0[kb * 4]);
                zacc += dot4_(a4, h4);
                racc += dot4_(b4, h4);
            }
            const float zv = sigmoidf_(useXP ? zacc : (zacc + bzi));
            const float rv = sigmoidf_(useXP ? racc : (racc - bri));
            RHs0[i] = rv * h;
            __syncthreads();

            float macc;
            if (useXP) {
                macc = XPh[t * S2 + i];
            } else {
                macc = 0.0f;
                for (int kb = 0; kb < WKB; ++kb) {
                    float4 a4 = Wh4[kb * S2 + i];
                    float4 x4 = *(const float4*)(&xs0[kb * 4]);
                    macc += dot4_(a4, x4);
                }
            }
            for (int kb = 0; kb < NKB; ++kb) {
                float4 a4 = Uh4[kb * S2 + i];
                float4 h4 = *(const float4*)(&RHs0[kb * 4]);
                macc += dot4_(a4, h4);
            }
            const float mm = tanhf(useXP ? macc : (macc + bhi));
            const float hn = zv * h + (1.0f - zv) * mm;
            if (rb == rp) atomicAdd(addr, hn - h);
            else storeLLC_(addr, hn);
            __syncthreads();
            if (i == 0)
                __hip_atomic_fetch_add(&flagArr[t], NSLICE, __ATOMIC_RELEASE,
                                       __HIP_MEMORY_SCOPE_AGENT);
        }
    }
}

// ---------------- host launcher ----------------

extern "C" void kernel_launch(void* const* d_in, const int* in_sizes, int n_in,
                              void* d_out, int out_size, void* d_ws, size_t ws_size,
                              hipStream_t stream) {
    const float* x  = (const float*)d_in[0];
    const int*   b  = (const int*)d_in[1];
    const int*   p  = (const int*)d_in[2];
    const float* Wz = (const float*)d_in[3];
    const float* Wr = (const float*)d_in[4];
    const float* Wh = (const float*)d_in[5];
    const float* Uz = (const float*)d_in[6];
    const float* Ur = (const float*)d_in[7];
    const float* Uh = (const float*)d_in[8];
    const float* bz = (const float*)d_in[9];
    const float* br = (const float*)d_in[10];
    const float* bh = (const float*)d_in[11];
    const float* table0 = (const float*)d_in[12];
    float* out = (float*)d_out;

    float* UzT = (float*)d_ws;
    float* UrT = UzT + S2 * S2;
    float* UhT = UrT + S2 * S2;
    float* WzT = UhT + S2 * S2;
    float* WrT = WzT + S2 * SIT;
    float* WhT = WrT + S2 * SIT;
    int* cnt = (int*)(WhT + S2 * SIT);
    int* cur = cnt + NPL;
    int* bas = cur + NPL;
    int* list = bas + NPL;
    int* pred = list + NEV;
    int* order = pred + NEV;
    int* levelStart = order + T_STEPS;
    int* numLevels = levelStart + 260;   // [0]=maxLev, [1]=cutoff (+2 pad)
    int* flagArr = numLevels + 4;
    int* rhCnt = flagArr + T_STEPS;

    size_t baseFloats = (size_t)(3 * S2 * S2 + 3 * S2 * SIT)
                      + 3 * NPL + 2 * NEV + T_STEPS + 264 + T_STEPS + MAXB;
    baseFloats = (baseFloats + 255) & ~(size_t)255;
    float* RHstage = (float*)d_ws + baseFloats;
    size_t rhFloats = (size_t)MAXB * S2;
    size_t xpFloats = 3ull * T_STEPS * S2;

    int useSlice = 0, useXP = 0;
    float *XPz;
    if (ws_size >= (baseFloats + rhFloats + xpFloats) * 4ull) {
        useSlice = 1; useXP = 1; XPz = RHstage + rhFloats;
    } else if (ws_size >= (baseFloats + xpFloats) * 4ull) {
        useXP = 1; XPz = RHstage;            // XP takes the RH position
    } else {
        XPz = RHstage;                       // unused
    }
    float* XPr = XPz + (size_t)T_STEPS * S2;
    float* XPh = XPr + (size_t)T_STEPS * S2;

    hipLaunchKernelGGL(k_trans, dim3(1024, 6), dim3(256), 0, stream,
                       Uz, Ur, Uh, Wz, Wr, Wh, UzT, UrT, UhT, WzT, WrT, WhT);
    hipLaunchKernelGGL(k_zero, dim3((NPL + 255) / 256), dim3(256), 0, stream, cnt);
    hipLaunchKernelGGL(k_count, dim3((NEV + 255) / 256), dim3(256), 0, stream, b, p, cnt);
    hipLaunchKernelGGL(k_scan, dim3(1), dim3(1024), 0, stream, cnt, bas, cur);
    hipLaunchKernelGGL(k_place, dim3((NEV + 255) / 256), dim3(256), 0, stream, b, p, cur, list);
    hipLaunchKernelGGL(k_pred, dim3((NPL + 255) / 256), dim3(256), 0, stream, bas, cnt, list, pred);
    hipLaunchKernelGGL(k_levels, dim3(1), dim3(1024), 0, stream,
                       pred, order, levelStart, numLevels);

    int n4 = NPL * SS / 4;
    hipLaunchKernelGGL(k_copy, dim3((n4 + 255) / 256), dim3(256), 0, stream,
                       (const float4*)table0, (float4*)out, n4);
    if (useXP) {
        hipLaunchKernelGGL(k_xp, dim3(T_STEPS / 16), dim3(512), 0, stream,
                           x, WzT, WrT, WhT, bz, br, bh, XPz, XPr, XPh);
    }

    // grid sizing: query capacity, clamp DOWN only (never exceed what fits)
    int occ = 0;
    if (hipOccupancyMaxActiveBlocksPerMultiprocessor(&occ, k_main, 512, 0) != hipSuccess)
        occ = 1;
    if (occ < 1) occ = 1;
    if (occ > 2) occ = 2;
    int gridSz = occ * 256;

    void* args[] = {
        (void*)&x, (void*)&b, (void*)&p,
        (void*)&WzT, (void*)&WrT, (void*)&WhT,
        (void*)&UzT, (void*)&UrT, (void*)&UhT,
        (void*)&bz, (void*)&br, (void*)&bh,
        (void*)&out,
        (void*)&order, (void*)&levelStart, (void*)&numLevels,
        (void*)&XPz, (void*)&XPr, (void*)&XPh,
        (void*)&pred, (void*)&flagArr, (void*)&rhCnt, (void*)&RHstage,
        (void*)&useXP, (void*)&useSlice
    };
    hipError_t e = hipLaunchCooperativeKernel((void*)k_main, dim3(gridSz), dim3(512), args, 0, stream);
    if (e != hipSuccess && gridSz != 256) {
        hipLaunchCooperativeKernel((void*)k_main, dim3(256), dim3(512), args, 0, stream);
    }
}